// Round 1
// baseline (480.366 us; speedup 1.0000x reference)
//
#include <hip/hip_runtime.h>
#include <hip/hip_bf16.h>

typedef __attribute__((ext_vector_type(8))) short short8;
typedef __attribute__((ext_vector_type(4))) short short4v;
typedef __attribute__((ext_vector_type(4))) float f32x4;

#define INV_TEMP 0.044194173824159216f

__device__ __forceinline__ ushort f2bf(float f) {
  unsigned u = __float_as_uint(f);
  unsigned r = (u + 0x7FFFu + ((u >> 16) & 1u)) >> 16;   // RNE
  return (ushort)r;
}

// ---------------- f32 -> bf16 conversion (4 elems/thread) ----------------
__global__ __launch_bounds__(256)
void cvt_f32_bf16(const float* __restrict__ in, ushort* __restrict__ out, int n4) {
  int i = blockIdx.x * 256 + threadIdx.x;
  if (i < n4) {
    f32x4 v = ((const f32x4*)in)[i];
    union { short4v s; ushort u[4]; } o;
    #pragma unroll
    for (int j = 0; j < 4; j++) o.u[j] = f2bf(v[j]);
    ((short4v*)out)[i] = o.s;
  }
}

// ---------------- weight transpose + cvt: W(K,N) f32 -> WT(N,K) bf16 ----------------
__global__ __launch_bounds__(256)
void transpose_cvt_w(const float* __restrict__ W, ushort* __restrict__ WT, int K, int N) {
  __shared__ float tile[32][33];
  const int n0 = blockIdx.x * 32, k0 = blockIdx.y * 32;
  const int tx = threadIdx.x & 31, ty = threadIdx.x >> 5;
  #pragma unroll
  for (int i = ty; i < 32; i += 8)
    tile[i][tx] = W[(long)(k0 + i) * N + n0 + tx];
  __syncthreads();
  #pragma unroll
  for (int i = ty; i < 32; i += 8)
    WT[(long)(n0 + i) * K + k0 + tx] = f2bf(tile[tx][i]);
}

// ---------------- bf16 transpose per batch: in (S,D) -> out (D,S) ----------------
__global__ __launch_bounds__(256)
void transpose_bf16(const ushort* __restrict__ in, ushort* __restrict__ out, int S, int D) {
  __shared__ ushort tile[32][33];
  const ushort* inb = in + (long)blockIdx.z * S * D;
  ushort* outb = out + (long)blockIdx.z * S * D;
  const int d0 = blockIdx.x * 32, s0 = blockIdx.y * 32;
  const int tx = threadIdx.x & 31, ty = threadIdx.x >> 5;
  #pragma unroll
  for (int i = ty; i < 32; i += 8)
    tile[i][tx] = inb[(long)(s0 + i) * D + d0 + tx];
  __syncthreads();
  #pragma unroll
  for (int i = ty; i < 32; i += 8)
    outb[(long)(d0 + i) * S + s0 + tx] = tile[tx][i];
}

// ---------------- LayerNorm over D=512, one wave per row, out bf16 (opt scale) ----------------
__global__ __launch_bounds__(256)
void ln_kernel(const float* __restrict__ X, const float* __restrict__ g,
               const float* __restrict__ be, ushort* __restrict__ out, float scale) {
  const int row = blockIdx.x * 4 + (threadIdx.x >> 6);
  const int lane = threadIdx.x & 63;
  const float* x = X + (long)row * 512 + lane * 8;
  f32x4 v0 = *(const f32x4*)x;
  f32x4 v1 = *(const f32x4*)(x + 4);
  float s = v0[0]+v0[1]+v0[2]+v0[3]+v1[0]+v1[1]+v1[2]+v1[3];
  float ss = v0[0]*v0[0]+v0[1]*v0[1]+v0[2]*v0[2]+v0[3]*v0[3]
           + v1[0]*v1[0]+v1[1]*v1[1]+v1[2]*v1[2]+v1[3]*v1[3];
  #pragma unroll
  for (int off = 32; off; off >>= 1) { s += __shfl_xor(s, off); ss += __shfl_xor(ss, off); }
  const float mean = s * (1.0f/512.0f);
  const float var  = ss * (1.0f/512.0f) - mean*mean;
  const float rs = rsqrtf(var + 1e-6f);
  f32x4 g0 = *(const f32x4*)(g + lane*8);
  f32x4 g1 = *(const f32x4*)(g + lane*8 + 4);
  f32x4 b0 = *(const f32x4*)(be + lane*8);
  f32x4 b1 = *(const f32x4*)(be + lane*8 + 4);
  union { short8 v; ushort u[8]; } o;
  #pragma unroll
  for (int j = 0; j < 4; j++) o.u[j]     = f2bf(((v0[j]-mean)*rs*g0[j] + b0[j]) * scale);
  #pragma unroll
  for (int j = 0; j < 4; j++) o.u[4 + j] = f2bf(((v1[j]-mean)*rs*g1[j] + b1[j]) * scale);
  *(short8*)(out + (long)row * 512 + lane * 8) = o.v;
}

// ---------------- row-normalize exp-scores: f32 in-place + bf16 copy ----------------
__global__ __launch_bounds__(256)
void softmax_norm(float* __restrict__ P, ushort* __restrict__ Pb) {
  const long row = blockIdx.x;
  float* p = P + row * 2048;
  ushort* pb = Pb + row * 2048;
  const int t = threadIdx.x;
  f32x4 a = *(const f32x4*)(p + t*8);
  f32x4 b = *(const f32x4*)(p + t*8 + 4);
  float s = a[0]+a[1]+a[2]+a[3]+b[0]+b[1]+b[2]+b[3];
  #pragma unroll
  for (int off = 32; off; off >>= 1) s += __shfl_xor(s, off);
  __shared__ float red[4];
  if ((t & 63) == 0) red[t >> 6] = s;
  __syncthreads();
  const float inv = 1.0f / (red[0] + red[1] + red[2] + red[3]);
  union { short8 v; ushort u[8]; } o;
  f32x4 an, bn;
  #pragma unroll
  for (int j = 0; j < 4; j++) { an[j] = a[j]*inv; o.u[j]   = f2bf(an[j]); }
  #pragma unroll
  for (int j = 0; j < 4; j++) { bn[j] = b[j]*inv; o.u[4+j] = f2bf(bn[j]); }
  *(f32x4*)(p + t*8) = an;
  *(f32x4*)(p + t*8 + 4) = bn;
  *(short8*)(pb + t*8) = o.v;
}

// ---------------- TN GEMM: C[M,N] = A[M,K] * BT[N,K]^T (+bias, epilogue) ----------------
// EPI: 0 = none, 1 = relu, 2 = exp (with mask)
template<int EPI, bool HAS_BIAS, bool OUT_BF16>
__global__ __launch_bounds__(256)
void gemm_tn(const ushort* __restrict__ A, const ushort* __restrict__ Bt,
             const float* __restrict__ bias, const int* __restrict__ mask,
             float* __restrict__ Cf, ushort* __restrict__ Cb,
             int M, int N, int K,
             long sA, long sB, long sC, long sMask) {
  __shared__ ushort As[128 * 64];
  __shared__ ushort Bs[128 * 64];
  const int tid = threadIdx.x;
  const int lane = tid & 63;
  const int wave = tid >> 6;
  const int wr = wave >> 1, wc = wave & 1;
  const long zb = blockIdx.z;
  const ushort* Ab = A + zb * sA + (long)blockIdx.y * 128 * K;
  const ushort* Bb = Bt + zb * sB + (long)blockIdx.x * 128 * K;

  f32x4 acc[4][4];
  #pragma unroll
  for (int m = 0; m < 4; m++)
    #pragma unroll
    for (int n = 0; n < 4; n++)
      acc[m][n] = f32x4{0.f, 0.f, 0.f, 0.f};

  for (int kt = 0; kt < K; kt += 64) {
    // stage 128x64 A-tile and B-tile, XOR-swizzled rows (16B granules)
    #pragma unroll
    for (int i = 0; i < 4; i++) {
      const int c = i * 256 + tid;
      const int row = c >> 3;
      const int c8 = c & 7;
      const int ldsOff = (row << 7) | (((c8 << 4)) ^ ((row & 7) << 4));
      *(short8*)((char*)As + ldsOff) = *(const short8*)(Ab + (long)row * K + kt + c8 * 8);
      *(short8*)((char*)Bs + ldsOff) = *(const short8*)(Bb + (long)row * K + kt + c8 * 8);
    }
    __syncthreads();
    #pragma unroll
    for (int ks = 0; ks < 2; ks++) {
      short8 af[4], bfr[4];
      const int kb = ks * 64 + ((lane >> 4) << 4);
      #pragma unroll
      for (int m = 0; m < 4; m++) {
        const int row = wr * 64 + m * 16 + (lane & 15);
        af[m] = *(const short8*)((const char*)As + ((row << 7) | (kb ^ ((row & 7) << 4))));
      }
      #pragma unroll
      for (int n = 0; n < 4; n++) {
        const int col = wc * 64 + n * 16 + (lane & 15);
        bfr[n] = *(const short8*)((const char*)Bs + ((col << 7) | (kb ^ ((col & 7) << 4))));
      }
      #pragma unroll
      for (int m = 0; m < 4; m++)
        #pragma unroll
        for (int n = 0; n < 4; n++)
          acc[m][n] = __builtin_amdgcn_mfma_f32_16x16x32_bf16(af[m], bfr[n], acc[m][n], 0, 0, 0);
    }
    __syncthreads();
  }

  // epilogue: D[row][col], col = lane&15, row = (lane>>4)*4 + r  [m89/m91 layout]
  const int colbase = blockIdx.x * 128 + wc * 64;
  const int rowbase = blockIdx.y * 128 + wr * 64;
  const int c_lane = lane & 15;
  const int r_lane = (lane >> 4) << 2;
  #pragma unroll
  for (int n = 0; n < 4; n++) {
    const int col = colbase + n * 16 + c_lane;
    const float bv = HAS_BIAS ? bias[col] : 0.0f;
    #pragma unroll
    for (int m = 0; m < 4; m++) {
      const int rbase = rowbase + m * 16 + r_lane;
      #pragma unroll
      for (int r4 = 0; r4 < 4; r4++) {
        const int row = rbase + r4;
        float vv = acc[m][n][r4] + bv;
        if constexpr (EPI == 1) vv = fmaxf(vv, 0.0f);
        if constexpr (EPI == 2) {
          const int mk = mask[zb * sMask + (long)row * N + col];
          vv = mk ? __expf(vv) : 0.0f;
        }
        const long off = zb * sC + (long)row * N + col;
        if constexpr (OUT_BF16) Cb[off] = f2bf(vv);
        else                    Cf[off] = vv;
      }
    }
  }
}

extern "C" void kernel_launch(void* const* d_in, const int* in_sizes, int n_in,
                              void* d_out, int out_size, void* d_ws, size_t ws_size,
                              hipStream_t stream) {
  const float* q    = (const float*)d_in[0];
  const float* k    = (const float*)d_in[1];
  const float* v    = (const float*)d_in[2];
  const int*   mask = (const int*)d_in[3];
  const float* Wq   = (const float*)d_in[4];
  const float* bq   = (const float*)d_in[5];
  const float* Wk   = (const float*)d_in[6];
  const float* bk   = (const float*)d_in[7];
  const float* Wv   = (const float*)d_in[8];
  const float* bv   = (const float*)d_in[9];
  const float* g_q  = (const float*)d_in[10];
  const float* be_q = (const float*)d_in[11];
  const float* g_k  = (const float*)d_in[12];
  const float* be_k = (const float*)d_in[13];
  const float* g_v  = (const float*)d_in[14];
  const float* be_v = (const float*)d_in[15];
  const float* W1   = (const float*)d_in[16];
  const float* b1   = (const float*)d_in[17];
  const float* W2   = (const float*)d_in[18];
  const float* b2   = (const float*)d_in[19];

  float* out_mlp  = (float*)d_out;                 // (8,2048,1024)
  float* out_res  = out_mlp + 16777216L;           // (8,2048,1,512)
  float* out_attn = out_res + 8388608L;            // (8,2048,2048)

  char* w = (char*)d_ws;
  ushort* act     = (ushort*)(w);                   // 33.5MB: bf16 activations (q/k/v, reused)
  ushort* qn      = (ushort*)(w);                   // reuses act after projections done
  ushort* kn      = (ushort*)(w + 16777216UL);
  float*  kp      = (float*)(w + 33554432UL);       // 33.5MB
  ushort* attn_bf = (ushort*)(w + 33554432UL);      // 67MB, reuses kp+vp after LN
  float*  vp      = (float*)(w + 67108864UL);       // 33.5MB
  ushort* vn      = (ushort*)(w + 100663296UL);     // 16.7MB
  ushort* vnT     = (ushort*)(w + 117440512UL);     // 16.7MB
  ushort* pv      = (ushort*)(w + 134217728UL);     // 16.7MB
  ushort* h       = (ushort*)(w + 150994944UL);     // 16.7MB
  ushort* wqT     = (ushort*)(w + 167772160UL);     // (512,1024) bf16
  ushort* wkT     = (ushort*)(w + 168820736UL);
  ushort* wvT     = (ushort*)(w + 169869312UL);
  ushort* w1T     = (ushort*)(w + 170917888UL);     // (512,512)
  ushort* w2T     = (ushort*)(w + 171442176UL);     // (1024,512)

  dim3 blk(256);

  // weights -> bf16 transposed
  transpose_cvt_w<<<dim3(16, 32), blk, 0, stream>>>(Wq, wqT, 1024, 512);
  transpose_cvt_w<<<dim3(16, 32), blk, 0, stream>>>(Wk, wkT, 1024, 512);
  transpose_cvt_w<<<dim3(16, 32), blk, 0, stream>>>(Wv, wvT, 1024, 512);
  transpose_cvt_w<<<dim3(16, 16), blk, 0, stream>>>(W1, w1T, 512, 512);
  transpose_cvt_w<<<dim3(32, 16), blk, 0, stream>>>(W2, w2T, 512, 1024);

  // projections (A bf16-converted in place of the shared act buffer)
  cvt_f32_bf16<<<16384, blk, 0, stream>>>(q, act, 4194304);
  gemm_tn<0, true, false><<<dim3(4, 128, 1), blk, 0, stream>>>(
      act, wqT, bq, nullptr, out_res, nullptr, 16384, 512, 1024, 0, 0, 0, 0);
  cvt_f32_bf16<<<16384, blk, 0, stream>>>(k, act, 4194304);
  gemm_tn<0, true, false><<<dim3(4, 128, 1), blk, 0, stream>>>(
      act, wkT, bk, nullptr, kp, nullptr, 16384, 512, 1024, 0, 0, 0, 0);
  cvt_f32_bf16<<<16384, blk, 0, stream>>>(v, act, 4194304);
  gemm_tn<0, true, false><<<dim3(4, 128, 1), blk, 0, stream>>>(
      act, wvT, bv, nullptr, vp, nullptr, 16384, 512, 1024, 0, 0, 0, 0);

  // per-token LayerNorms (1/sqrt(DK) folded into qn)
  ln_kernel<<<4096, blk, 0, stream>>>(out_res, g_q, be_q, qn, INV_TEMP);
  ln_kernel<<<4096, blk, 0, stream>>>(kp, g_k, be_k, kn, 1.0f);
  ln_kernel<<<4096, blk, 0, stream>>>(vp, g_v, be_v, vn, 1.0f);

  // vn -> vnT for PV's B-operand
  transpose_bf16<<<dim3(16, 64, 8), blk, 0, stream>>>(vn, vnT, 2048, 512);

  // scores = exp(qn.kn^T) with mask, written to attn output region
  gemm_tn<2, false, false><<<dim3(16, 16, 8), blk, 0, stream>>>(
      qn, kn, nullptr, mask, out_attn, nullptr, 2048, 2048, 512,
      (long)2048 * 512, (long)2048 * 512, (long)2048 * 2048, (long)2048 * 2048);

  // row-normalize: attn f32 (output) + attn bf16 (PV input)
  softmax_norm<<<16384, blk, 0, stream>>>(out_attn, attn_bf);

  // PV
  gemm_tn<0, false, true><<<dim3(4, 16, 8), blk, 0, stream>>>(
      attn_bf, vnT, nullptr, nullptr, nullptr, pv, 2048, 512, 2048,
      (long)2048 * 2048, (long)512 * 2048, (long)2048 * 512, 0);

  // MLP
  gemm_tn<1, true, true><<<dim3(4, 128, 1), blk, 0, stream>>>(
      pv, w1T, b1, nullptr, nullptr, h, 16384, 512, 512, 0, 0, 0, 0);
  gemm_tn<0, true, false><<<dim3(8, 128, 1), blk, 0, stream>>>(
      h, w2T, b2, nullptr, out_mlp, nullptr, 16384, 1024, 512, 0, 0, 0, 0);
}

// Round 2
// 470.461 us; speedup vs baseline: 1.0211x; 1.0211x over previous
//
#include <hip/hip_runtime.h>
#include <hip/hip_bf16.h>

typedef __attribute__((ext_vector_type(8))) short short8;
typedef __attribute__((ext_vector_type(4))) short short4v;
typedef __attribute__((ext_vector_type(4))) float f32x4;

#define INV_TEMP 0.044194173824159216f

__device__ __forceinline__ ushort f2bf(float f) {
  unsigned u = __float_as_uint(f);
  unsigned r = (u + 0x7FFFu + ((u >> 16) & 1u)) >> 16;   // RNE
  return (ushort)r;
}

// async global->LDS, 16B per lane. HW semantics: LDS dest = wave-uniform base
// + lane*16 (we pass exactly base+lane*16); global source is per-lane.
__device__ __forceinline__ void gload_lds16(const void* g, void* l) {
  __builtin_amdgcn_global_load_lds(
      (const __attribute__((address_space(1))) unsigned int*)(unsigned long long)(uintptr_t)g,
      (__attribute__((address_space(3))) unsigned int*)(unsigned)(uintptr_t)l,
      16, 0, 0);
}

// ---------------- f32 -> bf16 conversion (4 elems/thread) ----------------
__global__ __launch_bounds__(256)
void cvt_f32_bf16(const float* __restrict__ in, ushort* __restrict__ out, int n4) {
  int i = blockIdx.x * 256 + threadIdx.x;
  if (i < n4) {
    f32x4 v = ((const f32x4*)in)[i];
    union { short4v s; ushort u[4]; } o;
    #pragma unroll
    for (int j = 0; j < 4; j++) o.u[j] = f2bf(v[j]);
    ((short4v*)out)[i] = o.s;
  }
}

// ---------------- weight transpose + cvt: W(K,N) f32 -> WT(N,K) bf16 ----------------
__global__ __launch_bounds__(256)
void transpose_cvt_w(const float* __restrict__ W, ushort* __restrict__ WT, int K, int N) {
  __shared__ float tile[32][33];
  const int n0 = blockIdx.x * 32, k0 = blockIdx.y * 32;
  const int tx = threadIdx.x & 31, ty = threadIdx.x >> 5;
  #pragma unroll
  for (int i = ty; i < 32; i += 8)
    tile[i][tx] = W[(long)(k0 + i) * N + n0 + tx];
  __syncthreads();
  #pragma unroll
  for (int i = ty; i < 32; i += 8)
    WT[(long)(n0 + i) * K + k0 + tx] = f2bf(tile[tx][i]);
}

// ---------------- bf16 transpose per batch: in (S,D) -> out (D,S) ----------------
__global__ __launch_bounds__(256)
void transpose_bf16(const ushort* __restrict__ in, ushort* __restrict__ out, int S, int D) {
  __shared__ ushort tile[32][33];
  const ushort* inb = in + (long)blockIdx.z * S * D;
  ushort* outb = out + (long)blockIdx.z * S * D;
  const int d0 = blockIdx.x * 32, s0 = blockIdx.y * 32;
  const int tx = threadIdx.x & 31, ty = threadIdx.x >> 5;
  #pragma unroll
  for (int i = ty; i < 32; i += 8)
    tile[i][tx] = inb[(long)(s0 + i) * D + d0 + tx];
  __syncthreads();
  #pragma unroll
  for (int i = ty; i < 32; i += 8)
    outb[(long)(d0 + i) * S + s0 + tx] = tile[tx][i];
}

// ---------------- LayerNorm over D=512, one wave per row, out bf16 (opt scale) ----------------
__global__ __launch_bounds__(256)
void ln_kernel(const float* __restrict__ X, const float* __restrict__ g,
               const float* __restrict__ be, ushort* __restrict__ out, float scale) {
  const int row = blockIdx.x * 4 + (threadIdx.x >> 6);
  const int lane = threadIdx.x & 63;
  const float* x = X + (long)row * 512 + lane * 8;
  f32x4 v0 = *(const f32x4*)x;
  f32x4 v1 = *(const f32x4*)(x + 4);
  float s = v0[0]+v0[1]+v0[2]+v0[3]+v1[0]+v1[1]+v1[2]+v1[3];
  float ss = v0[0]*v0[0]+v0[1]*v0[1]+v0[2]*v0[2]+v0[3]*v0[3]
           + v1[0]*v1[0]+v1[1]*v1[1]+v1[2]*v1[2]+v1[3]*v1[3];
  #pragma unroll
  for (int off = 32; off; off >>= 1) { s += __shfl_xor(s, off); ss += __shfl_xor(ss, off); }
  const float mean = s * (1.0f/512.0f);
  const float var  = ss * (1.0f/512.0f) - mean*mean;
  const float rs = rsqrtf(var + 1e-6f);
  f32x4 g0 = *(const f32x4*)(g + lane*8);
  f32x4 g1 = *(const f32x4*)(g + lane*8 + 4);
  f32x4 b0 = *(const f32x4*)(be + lane*8);
  f32x4 b1 = *(const f32x4*)(be + lane*8 + 4);
  union { short8 v; ushort u[8]; } o;
  #pragma unroll
  for (int j = 0; j < 4; j++) o.u[j]     = f2bf(((v0[j]-mean)*rs*g0[j] + b0[j]) * scale);
  #pragma unroll
  for (int j = 0; j < 4; j++) o.u[4 + j] = f2bf(((v1[j]-mean)*rs*g1[j] + b1[j]) * scale);
  *(short8*)(out + (long)row * 512 + lane * 8) = o.v;
}

// ---------------- row-normalize exp-scores: f32 in-place + bf16 copy ----------------
__global__ __launch_bounds__(256)
void softmax_norm(float* __restrict__ P, ushort* __restrict__ Pb) {
  const long row = blockIdx.x;
  float* p = P + row * 2048;
  ushort* pb = Pb + row * 2048;
  const int t = threadIdx.x;
  f32x4 a = *(const f32x4*)(p + t*8);
  f32x4 b = *(const f32x4*)(p + t*8 + 4);
  float s = a[0]+a[1]+a[2]+a[3]+b[0]+b[1]+b[2]+b[3];
  #pragma unroll
  for (int off = 32; off; off >>= 1) s += __shfl_xor(s, off);
  __shared__ float red[4];
  if ((t & 63) == 0) red[t >> 6] = s;
  __syncthreads();
  const float inv = 1.0f / (red[0] + red[1] + red[2] + red[3]);
  union { short8 v; ushort u[8]; } o;
  f32x4 an, bn;
  #pragma unroll
  for (int j = 0; j < 4; j++) { an[j] = a[j]*inv; o.u[j]   = f2bf(an[j]); }
  #pragma unroll
  for (int j = 0; j < 4; j++) { bn[j] = b[j]*inv; o.u[4+j] = f2bf(bn[j]); }
  *(f32x4*)(p + t*8) = an;
  *(f32x4*)(p + t*8 + 4) = bn;
  *(short8*)(pb + t*8) = o.v;
}

// ---------------- TN GEMM: C[M,N] = A[M,K] * BT[N,K]^T (+bias, epilogue) ----------------
// EPI: 0 = none, 1 = relu, 2 = exp (with mask)
// Staging: global_load_lds width=16, LINEAR LDS dest, inverse-swizzled SOURCE;
// reads use the same XOR involution (rule 21 both-sides pattern).
// XCD-aware bijective chunk swizzle on the linearized block index (T1).
template<int EPI, bool HAS_BIAS, bool OUT_BF16>
__global__ __launch_bounds__(256)
void gemm_tn(const ushort* __restrict__ A, const ushort* __restrict__ Bt,
             const float* __restrict__ bias, const int* __restrict__ mask,
             float* __restrict__ Cf, ushort* __restrict__ Cb,
             int M, int N, int K,
             long sA, long sB, long sC, long sMask) {
  __shared__ ushort As[128 * 64];
  __shared__ ushort Bs[128 * 64];
  const int tid = threadIdx.x;
  const int lane = tid & 63;
  const int wave = tid >> 6;
  const int wr = wave >> 1, wc = wave & 1;

  // ---- XCD swizzle: linearize (x fastest = dispatch order), chunk-remap ----
  const int gx = gridDim.x, gy = gridDim.y;
  int lin = blockIdx.x + gx * (blockIdx.y + gy * blockIdx.z);
  const int nwg = gx * gy * (int)gridDim.z;
  int swz = lin;
  if ((nwg & 7) == 0) {
    const int q8 = nwg >> 3;
    swz = (lin & 7) * q8 + (lin >> 3);
  }
  const int bx = swz % gx;
  const int tmp = swz / gx;
  const int by = tmp % gy;
  const int bz = tmp / gy;

  const long zb = bz;
  const ushort* Ab = A + zb * sA + (long)by * 128 * K;
  const ushort* Bb = Bt + zb * sB + (long)bx * 128 * K;

  f32x4 acc[4][4];
  #pragma unroll
  for (int m = 0; m < 4; m++)
    #pragma unroll
    for (int n = 0; n < 4; n++)
      acc[m][n] = f32x4{0.f, 0.f, 0.f, 0.f};

  for (int kt = 0; kt < K; kt += 64) {
    // stage 128x64 tiles: LDS slot (row, g) gets global granule g^(row&7)
    #pragma unroll
    for (int i = 0; i < 4; i++) {
      const int c = i * 256 + tid;            // 0..1023
      const int row = c >> 3;
      const int g = c & 7;
      const int gsrc = g ^ (row & 7);
      gload_lds16(Ab + (long)row * K + kt + gsrc * 8, (char*)As + c * 16);
      gload_lds16(Bb + (long)row * K + kt + gsrc * 8, (char*)Bs + c * 16);
    }
    __syncthreads();   // compiler emits vmcnt(0) drain before s_barrier
    #pragma unroll
    for (int ks = 0; ks < 2; ks++) {
      short8 af[4], bfr[4];
      const int kb = ks * 64 + ((lane >> 4) << 4);
      #pragma unroll
      for (int m = 0; m < 4; m++) {
        const int row = wr * 64 + m * 16 + (lane & 15);
        af[m] = *(const short8*)((const char*)As + ((row << 7) | (kb ^ ((row & 7) << 4))));
      }
      #pragma unroll
      for (int n = 0; n < 4; n++) {
        const int col = wc * 64 + n * 16 + (lane & 15);
        bfr[n] = *(const short8*)((const char*)Bs + ((col << 7) | (kb ^ ((col & 7) << 4))));
      }
      #pragma unroll
      for (int m = 0; m < 4; m++)
        #pragma unroll
        for (int n = 0; n < 4; n++)
          acc[m][n] = __builtin_amdgcn_mfma_f32_16x16x32_bf16(af[m], bfr[n], acc[m][n], 0, 0, 0);
    }
    __syncthreads();
  }

  // epilogue: D[row][col], col = lane&15, row = (lane>>4)*4 + r  [m89/m91 layout]
  const int colbase = bx * 128 + wc * 64;
  const int rowbase = by * 128 + wr * 64;
  const int c_lane = lane & 15;
  const int r_lane = (lane >> 4) << 2;
  #pragma unroll
  for (int n = 0; n < 4; n++) {
    const int col = colbase + n * 16 + c_lane;
    const float bv = HAS_BIAS ? bias[col] : 0.0f;
    #pragma unroll
    for (int m = 0; m < 4; m++) {
      const int rbase = rowbase + m * 16 + r_lane;
      #pragma unroll
      for (int r4 = 0; r4 < 4; r4++) {
        const int row = rbase + r4;
        float vv = acc[m][n][r4] + bv;
        if constexpr (EPI == 1) vv = fmaxf(vv, 0.0f);
        if constexpr (EPI == 2) {
          const int mk = mask[zb * sMask + (long)row * N + col];
          vv = mk ? __expf(vv) : 0.0f;
        }
        const long off = zb * sC + (long)row * N + col;
        if constexpr (OUT_BF16) Cb[off] = f2bf(vv);
        else                    Cf[off] = vv;
      }
    }
  }
}

extern "C" void kernel_launch(void* const* d_in, const int* in_sizes, int n_in,
                              void* d_out, int out_size, void* d_ws, size_t ws_size,
                              hipStream_t stream) {
  const float* q    = (const float*)d_in[0];
  const float* k    = (const float*)d_in[1];
  const float* v    = (const float*)d_in[2];
  const int*   mask = (const int*)d_in[3];
  const float* Wq   = (const float*)d_in[4];
  const float* bq   = (const float*)d_in[5];
  const float* Wk   = (const float*)d_in[6];
  const float* bk   = (const float*)d_in[7];
  const float* Wv   = (const float*)d_in[8];
  const float* bv   = (const float*)d_in[9];
  const float* g_q  = (const float*)d_in[10];
  const float* be_q = (const float*)d_in[11];
  const float* g_k  = (const float*)d_in[12];
  const float* be_k = (const float*)d_in[13];
  const float* g_v  = (const float*)d_in[14];
  const float* be_v = (const float*)d_in[15];
  const float* W1   = (const float*)d_in[16];
  const float* b1   = (const float*)d_in[17];
  const float* W2   = (const float*)d_in[18];
  const float* b2   = (const float*)d_in[19];

  float* out_mlp  = (float*)d_out;                 // (8,2048,1024)
  float* out_res  = out_mlp + 16777216L;           // (8,2048,1,512)
  float* out_attn = out_res + 8388608L;            // (8,2048,2048)

  char* w = (char*)d_ws;
  ushort* act     = (ushort*)(w);                   // 33.5MB: bf16 activations (q/k/v, reused)
  ushort* qn      = (ushort*)(w);                   // reuses act after projections done
  ushort* kn      = (ushort*)(w + 16777216UL);
  float*  kp      = (float*)(w + 33554432UL);       // 33.5MB
  ushort* attn_bf = (ushort*)(w + 33554432UL);      // 67MB, reuses kp+vp after LN
  float*  vp      = (float*)(w + 67108864UL);       // 33.5MB
  ushort* vn      = (ushort*)(w + 100663296UL);     // 16.7MB
  ushort* vnT     = (ushort*)(w + 117440512UL);     // 16.7MB
  ushort* pv      = (ushort*)(w + 134217728UL);     // 16.7MB
  ushort* h       = (ushort*)(w + 150994944UL);     // 16.7MB
  ushort* wqT     = (ushort*)(w + 167772160UL);     // (512,1024) bf16
  ushort* wkT     = (ushort*)(w + 168820736UL);
  ushort* wvT     = (ushort*)(w + 169869312UL);
  ushort* w1T     = (ushort*)(w + 170917888UL);     // (512,512)
  ushort* w2T     = (ushort*)(w + 171442176UL);     // (1024,512)

  dim3 blk(256);

  // weights -> bf16 transposed
  transpose_cvt_w<<<dim3(16, 32), blk, 0, stream>>>(Wq, wqT, 1024, 512);
  transpose_cvt_w<<<dim3(16, 32), blk, 0, stream>>>(Wk, wkT, 1024, 512);
  transpose_cvt_w<<<dim3(16, 32), blk, 0, stream>>>(Wv, wvT, 1024, 512);
  transpose_cvt_w<<<dim3(16, 16), blk, 0, stream>>>(W1, w1T, 512, 512);
  transpose_cvt_w<<<dim3(32, 16), blk, 0, stream>>>(W2, w2T, 512, 1024);

  // projections (A bf16-converted in place of the shared act buffer)
  cvt_f32_bf16<<<16384, blk, 0, stream>>>(q, act, 4194304);
  gemm_tn<0, true, false><<<dim3(4, 128, 1), blk, 0, stream>>>(
      act, wqT, bq, nullptr, out_res, nullptr, 16384, 512, 1024, 0, 0, 0, 0);
  cvt_f32_bf16<<<16384, blk, 0, stream>>>(k, act, 4194304);
  gemm_tn<0, true, false><<<dim3(4, 128, 1), blk, 0, stream>>>(
      act, wkT, bk, nullptr, kp, nullptr, 16384, 512, 1024, 0, 0, 0, 0);
  cvt_f32_bf16<<<16384, blk, 0, stream>>>(v, act, 4194304);
  gemm_tn<0, true, false><<<dim3(4, 128, 1), blk, 0, stream>>>(
      act, wvT, bv, nullptr, vp, nullptr, 16384, 512, 1024, 0, 0, 0, 0);

  // per-token LayerNorms (1/sqrt(DK) folded into qn)
  ln_kernel<<<4096, blk, 0, stream>>>(out_res, g_q, be_q, qn, INV_TEMP);
  ln_kernel<<<4096, blk, 0, stream>>>(kp, g_k, be_k, kn, 1.0f);
  ln_kernel<<<4096, blk, 0, stream>>>(vp, g_v, be_v, vn, 1.0f);

  // vn -> vnT for PV's B-operand
  transpose_bf16<<<dim3(16, 64, 8), blk, 0, stream>>>(vn, vnT, 2048, 512);

  // scores = exp(qn.kn^T) with mask, written to attn output region
  gemm_tn<2, false, false><<<dim3(16, 16, 8), blk, 0, stream>>>(
      qn, kn, nullptr, mask, out_attn, nullptr, 2048, 2048, 512,
      (long)2048 * 512, (long)2048 * 512, (long)2048 * 2048, (long)2048 * 2048);

  // row-normalize: attn f32 (output) + attn bf16 (PV input)
  softmax_norm<<<16384, blk, 0, stream>>>(out_attn, attn_bf);

  // PV
  gemm_tn<0, false, true><<<dim3(4, 16, 8), blk, 0, stream>>>(
      attn_bf, vnT, nullptr, nullptr, nullptr, pv, 2048, 512, 2048,
      (long)2048 * 2048, (long)512 * 2048, (long)2048 * 512, 0);

  // MLP
  gemm_tn<1, true, true><<<dim3(4, 128, 1), blk, 0, stream>>>(
      pv, w1T, b1, nullptr, nullptr, h, 16384, 512, 512, 0, 0, 0, 0);
  gemm_tn<0, true, false><<<dim3(8, 128, 1), blk, 0, stream>>>(
      h, w2T, b2, nullptr, out_mlp, nullptr, 16384, 1024, 512, 0, 0, 0, 0);
}

// Round 3
// 424.358 us; speedup vs baseline: 1.1320x; 1.1086x over previous
//
#include <hip/hip_runtime.h>
#include <hip/hip_bf16.h>

typedef __attribute__((ext_vector_type(8))) short short8;
typedef __attribute__((ext_vector_type(4))) short short4v;
typedef __attribute__((ext_vector_type(4))) float f32x4;

#define INV_TEMP 0.044194173824159216f

__device__ __forceinline__ ushort f2bf(float f) {
  unsigned u = __float_as_uint(f);
  unsigned r = (u + 0x7FFFu + ((u >> 16) & 1u)) >> 16;   // RNE
  return (ushort)r;
}
__device__ __forceinline__ float bf2f(ushort u) {
  union { unsigned i; float f; } x; x.i = ((unsigned)u) << 16; return x.f;
}

// async global->LDS, 16B per lane. LDS dest = wave-uniform base + lane*16;
// global source is per-lane (so source carries the inverse swizzle).
__device__ __forceinline__ void gload_lds16(const void* g, void* l) {
  __builtin_amdgcn_global_load_lds(
      (const __attribute__((address_space(1))) unsigned int*)(unsigned long long)(uintptr_t)g,
      (__attribute__((address_space(3))) unsigned int*)(unsigned)(uintptr_t)l,
      16, 0, 0);
}

// ---------------- weight transpose + cvt: W(K,N) f32 -> WT(N,K) bf16 ----------------
__global__ __launch_bounds__(256)
void transpose_cvt_w(const float* __restrict__ W, ushort* __restrict__ WT, int K, int N) {
  __shared__ float tile[32][33];
  const int n0 = blockIdx.x * 32, k0 = blockIdx.y * 32;
  const int tx = threadIdx.x & 31, ty = threadIdx.x >> 5;
  #pragma unroll
  for (int i = ty; i < 32; i += 8)
    tile[i][tx] = W[(long)(k0 + i) * N + n0 + tx];
  __syncthreads();
  #pragma unroll
  for (int i = ty; i < 32; i += 8)
    WT[(long)(n0 + i) * K + k0 + tx] = f2bf(tile[tx][i]);
}

// same-shape 3-way variant (Wq/Wk/Wv are all (1024,512))
__global__ __launch_bounds__(256)
void transpose_cvt_w3(const float* __restrict__ W0, const float* __restrict__ W1,
                      const float* __restrict__ W2, ushort* __restrict__ T0,
                      ushort* __restrict__ T1, ushort* __restrict__ T2, int K, int N) {
  __shared__ float tile[32][33];
  const int z = blockIdx.z;
  const float* W = z == 0 ? W0 : (z == 1 ? W1 : W2);
  ushort* WT = z == 0 ? T0 : (z == 1 ? T1 : T2);
  const int n0 = blockIdx.x * 32, k0 = blockIdx.y * 32;
  const int tx = threadIdx.x & 31, ty = threadIdx.x >> 5;
  #pragma unroll
  for (int i = ty; i < 32; i += 8)
    tile[i][tx] = W[(long)(k0 + i) * N + n0 + tx];
  __syncthreads();
  #pragma unroll
  for (int i = ty; i < 32; i += 8)
    WT[(long)(n0 + i) * K + k0 + tx] = f2bf(tile[tx][i]);
}

// ---------------- bf16 transpose per batch: in (S,D) -> out (D,S) ----------------
__global__ __launch_bounds__(256)
void transpose_bf16(const ushort* __restrict__ in, ushort* __restrict__ out, int S, int D) {
  __shared__ ushort tile[32][33];
  const ushort* inb = in + (long)blockIdx.z * S * D;
  ushort* outb = out + (long)blockIdx.z * S * D;
  const int d0 = blockIdx.x * 32, s0 = blockIdx.y * 32;
  const int tx = threadIdx.x & 31, ty = threadIdx.x >> 5;
  #pragma unroll
  for (int i = ty; i < 32; i += 8)
    tile[i][tx] = inb[(long)(s0 + i) * D + d0 + tx];
  __syncthreads();
  #pragma unroll
  for (int i = ty; i < 32; i += 8)
    outb[(long)(d0 + i) * S + s0 + tx] = tile[tx][i];
}

// ---------------- merged LayerNorm over D=512 for q/k/v, one wave per row ----------------
__global__ __launch_bounds__(256)
void ln3_kernel(const float* __restrict__ Xq, const float* __restrict__ Xk,
                const float* __restrict__ Xv,
                const float* __restrict__ gq, const float* __restrict__ beq,
                const float* __restrict__ gk, const float* __restrict__ bek,
                const float* __restrict__ gv, const float* __restrict__ bev,
                ushort* __restrict__ Oq, ushort* __restrict__ Ok, ushort* __restrict__ Ov) {
  const int which = blockIdx.y;
  const float* X = which == 0 ? Xq : (which == 1 ? Xk : Xv);
  const float* g = which == 0 ? gq : (which == 1 ? gk : gv);
  const float* be = which == 0 ? beq : (which == 1 ? bek : bev);
  ushort* out = which == 0 ? Oq : (which == 1 ? Ok : Ov);
  const float scale = which == 0 ? INV_TEMP : 1.0f;

  const int row = blockIdx.x * 4 + (threadIdx.x >> 6);
  const int lane = threadIdx.x & 63;
  const float* x = X + (long)row * 512 + lane * 8;
  f32x4 v0 = *(const f32x4*)x;
  f32x4 v1 = *(const f32x4*)(x + 4);
  float s = v0[0]+v0[1]+v0[2]+v0[3]+v1[0]+v1[1]+v1[2]+v1[3];
  float ss = v0[0]*v0[0]+v0[1]*v0[1]+v0[2]*v0[2]+v0[3]*v0[3]
           + v1[0]*v1[0]+v1[1]*v1[1]+v1[2]*v1[2]+v1[3]*v1[3];
  #pragma unroll
  for (int off = 32; off; off >>= 1) { s += __shfl_xor(s, off); ss += __shfl_xor(ss, off); }
  const float mean = s * (1.0f/512.0f);
  const float var  = ss * (1.0f/512.0f) - mean*mean;
  const float rs = rsqrtf(var + 1e-6f);
  f32x4 g0 = *(const f32x4*)(g + lane*8);
  f32x4 g1 = *(const f32x4*)(g + lane*8 + 4);
  f32x4 b0 = *(const f32x4*)(be + lane*8);
  f32x4 b1 = *(const f32x4*)(be + lane*8 + 4);
  union { short8 v; ushort u[8]; } o;
  #pragma unroll
  for (int j = 0; j < 4; j++) o.u[j]     = f2bf(((v0[j]-mean)*rs*g0[j] + b0[j]) * scale);
  #pragma unroll
  for (int j = 0; j < 4; j++) o.u[4 + j] = f2bf(((v1[j]-mean)*rs*g1[j] + b1[j]) * scale);
  *(short8*)(out + (long)row * 512 + lane * 8) = o.v;
}

// ---------------- softmax finalize: Z from partials, write normalized f32 attn + invZ ----------------
__global__ __launch_bounds__(256)
void softmax_finalize(const ushort* __restrict__ Pb, const float* __restrict__ partial,
                      float* __restrict__ attn_f32, float* __restrict__ invZ) {
  const long row = blockIdx.x;          // zb*2048 + s
  const long zb = row >> 11;
  const long s = row & 2047;
  const int t = threadIdx.x;
  float z = 0.f;
  #pragma unroll
  for (int j = 0; j < 16; j++) z += partial[((zb * 16 + j) << 11) + s];
  const float inv = 1.0f / z;
  if (t == 0) invZ[row] = inv;
  const ushort* pb = Pb + (row << 11);
  float* po = attn_f32 + (row << 11);
  short8 vv = *(const short8*)(pb + t * 8);
  f32x4 o0, o1;
  #pragma unroll
  for (int j = 0; j < 4; j++) o0[j] = bf2f((ushort)vv[j]) * inv;
  #pragma unroll
  for (int j = 0; j < 4; j++) o1[j] = bf2f((ushort)vv[4 + j]) * inv;
  *(f32x4*)(po + t * 8) = o0;
  *(f32x4*)(po + t * 8 + 4) = o1;
}

// ---------------- TN GEMM: C[M,N] = A[M,K] * BT[N,K]^T (+bias, epilogue) ----------------
// EPI: 0 none, 1 relu, 2 exp+mask+row-sum partials (scores), 3 invZ row-scale (PV)
// A_F32: A is f32, reg-staged with fused cvt (swizzled ds_write); else global_load_lds.
template<int EPI, bool HAS_BIAS, bool OUT_BF16, bool A_F32>
__global__ __launch_bounds__(256)
void gemm_tn(const void* __restrict__ Av, const ushort* __restrict__ Bt,
             const float* __restrict__ bias, const int* __restrict__ mask,
             float* __restrict__ Cf, ushort* __restrict__ Cb,
             float* __restrict__ partial, const float* __restrict__ invZ,
             int M, int N, int K,
             long sA, long sB, long sC, long sMask) {
  __shared__ ushort As[128 * 64];
  __shared__ ushort Bs[128 * 64];
  const int tid = threadIdx.x;
  const int lane = tid & 63;
  const int wave = tid >> 6;
  const int wr = wave >> 1, wc = wave & 1;

  // ---- XCD-aware bijective chunk swizzle on linearized block index (T1) ----
  const int gx = gridDim.x, gy = gridDim.y;
  int lin = blockIdx.x + gx * (blockIdx.y + gy * blockIdx.z);
  const int nwg = gx * gy * (int)gridDim.z;
  int swz = lin;
  if ((nwg & 7) == 0) {
    const int q8 = nwg >> 3;
    swz = (lin & 7) * q8 + (lin >> 3);
  }
  const int bx = swz % gx;
  const int tmp = swz / gx;
  const int by = tmp % gy;
  const int bz = tmp / gy;

  const long zb = bz;
  const ushort* Ab = (const ushort*)Av + zb * sA + (long)by * 128 * K;
  const float*  Af = (const float*)Av + zb * sA + (long)by * 128 * K;
  const ushort* Bb = Bt + zb * sB + (long)bx * 128 * K;

  f32x4 acc[4][4];
  #pragma unroll
  for (int m = 0; m < 4; m++)
    #pragma unroll
    for (int n = 0; n < 4; n++)
      acc[m][n] = f32x4{0.f, 0.f, 0.f, 0.f};

  for (int kt = 0; kt < K; kt += 64) {
    #pragma unroll
    for (int i = 0; i < 4; i++) {
      const int c = i * 256 + tid;            // 0..1023 granules of 16B
      const int row = c >> 3;
      const int g = c & 7;
      const int gsrc = g ^ (row & 7);
      gload_lds16(Bb + (long)row * K + kt + gsrc * 8, (char*)Bs + c * 16);
      if constexpr (A_F32) {
        const f32x4 u0 = *(const f32x4*)(Af + (long)row * K + kt + g * 8);
        const f32x4 u1 = *(const f32x4*)(Af + (long)row * K + kt + g * 8 + 4);
        union { short8 s; ushort u[8]; } o;
        #pragma unroll
        for (int j = 0; j < 4; j++) { o.u[j] = f2bf(u0[j]); o.u[4 + j] = f2bf(u1[j]); }
        *(short8*)((char*)As + ((row << 7) | ((g << 4) ^ ((row & 7) << 4)))) = o.s;
      } else {
        gload_lds16(Ab + (long)row * K + kt + gsrc * 8, (char*)As + c * 16);
      }
    }
    __syncthreads();
    #pragma unroll
    for (int ks = 0; ks < 2; ks++) {
      short8 af[4], bfr[4];
      const int kb = ks * 64 + ((lane >> 4) << 4);
      #pragma unroll
      for (int m = 0; m < 4; m++) {
        const int row = wr * 64 + m * 16 + (lane & 15);
        af[m] = *(const short8*)((const char*)As + ((row << 7) | (kb ^ ((row & 7) << 4))));
      }
      #pragma unroll
      for (int n = 0; n < 4; n++) {
        const int col = wc * 64 + n * 16 + (lane & 15);
        bfr[n] = *(const short8*)((const char*)Bs + ((col << 7) | (kb ^ ((col & 7) << 4))));
      }
      #pragma unroll
      for (int m = 0; m < 4; m++)
        #pragma unroll
        for (int n = 0; n < 4; n++)
          acc[m][n] = __builtin_amdgcn_mfma_f32_16x16x32_bf16(af[m], bfr[n], acc[m][n], 0, 0, 0);
    }
    __syncthreads();
  }

  // epilogue: D[row][col], col = lane&15, row = (lane>>4)*4 + r  [m89/m91 layout]
  const int colbase = bx * 128 + wc * 64;
  const int rowbase = by * 128 + wr * 64;
  const int c_lane = lane & 15;
  const int r_lane = (lane >> 4) << 2;

  float rs_acc[4][4];
  if constexpr (EPI == 2) {
    #pragma unroll
    for (int m = 0; m < 4; m++)
      #pragma unroll
      for (int r4 = 0; r4 < 4; r4++) rs_acc[m][r4] = 0.f;
  }

  #pragma unroll
  for (int n = 0; n < 4; n++) {
    const int col = colbase + n * 16 + c_lane;
    const float bv = HAS_BIAS ? bias[col] : 0.0f;
    #pragma unroll
    for (int m = 0; m < 4; m++) {
      const int rbase = rowbase + m * 16 + r_lane;
      #pragma unroll
      for (int r4 = 0; r4 < 4; r4++) {
        const int row = rbase + r4;
        float vv = acc[m][n][r4] + bv;
        if constexpr (EPI == 1) vv = fmaxf(vv, 0.0f);
        if constexpr (EPI == 2) {
          const int mk = mask[zb * sMask + (long)row * N + col];
          vv = mk ? __expf(vv) : 0.0f;
          rs_acc[m][r4] += vv;
        }
        if constexpr (EPI == 3) vv *= invZ[zb * 2048 + row];
        const long off = zb * sC + (long)row * N + col;
        if constexpr (OUT_BF16) Cb[off] = f2bf(vv);
        else                    Cf[off] = vv;
      }
    }
  }

  if constexpr (EPI == 2) {
    // deterministic per-block row sums: 16-lane group reduce -> LDS -> global
    float (*red)[128] = (float(*)[128])As;   // reuse As (all waves past final barrier)
    #pragma unroll
    for (int m = 0; m < 4; m++)
      #pragma unroll
      for (int r4 = 0; r4 < 4; r4++) {
        float vsum = rs_acc[m][r4];
        vsum += __shfl_xor(vsum, 1);
        vsum += __shfl_xor(vsum, 2);
        vsum += __shfl_xor(vsum, 4);
        vsum += __shfl_xor(vsum, 8);
        if (c_lane == 0) red[wc][wr * 64 + m * 16 + r_lane + r4] = vsum;
      }
    __syncthreads();
    if (tid < 128)
      partial[((long)zb * 16 + bx) * 2048 + by * 128 + tid] = red[0][tid] + red[1][tid];
  }
}

extern "C" void kernel_launch(void* const* d_in, const int* in_sizes, int n_in,
                              void* d_out, int out_size, void* d_ws, size_t ws_size,
                              hipStream_t stream) {
  const float* q    = (const float*)d_in[0];
  const float* k    = (const float*)d_in[1];
  const float* v    = (const float*)d_in[2];
  const int*   mask = (const int*)d_in[3];
  const float* Wq   = (const float*)d_in[4];
  const float* bq   = (const float*)d_in[5];
  const float* Wk   = (const float*)d_in[6];
  const float* bk   = (const float*)d_in[7];
  const float* Wv   = (const float*)d_in[8];
  const float* bv   = (const float*)d_in[9];
  const float* g_q  = (const float*)d_in[10];
  const float* be_q = (const float*)d_in[11];
  const float* g_k  = (const float*)d_in[12];
  const float* be_k = (const float*)d_in[13];
  const float* g_v  = (const float*)d_in[14];
  const float* be_v = (const float*)d_in[15];
  const float* W1   = (const float*)d_in[16];
  const float* b1   = (const float*)d_in[17];
  const float* W2   = (const float*)d_in[18];
  const float* b2   = (const float*)d_in[19];

  float* out_mlp  = (float*)d_out;                 // (8,2048,1024)
  float* out_res  = out_mlp + 16777216L;           // (8,2048,1,512)
  float* out_attn = out_res + 8388608L;            // (8,2048,2048)

  char* w = (char*)d_ws;
  ushort* qn      = (ushort*)(w);                   // 16.7MB
  ushort* kn      = (ushort*)(w + 16777216UL);      // 16.7MB
  float*  kp      = (float*)(w + 33554432UL);       // 33.5MB (dead after LN)
  ushort* attn_bf = (ushort*)(w + 33554432UL);      // 67MB, reuses kp+vp
  float*  vp      = (float*)(w + 67108864UL);       // 33.5MB (dead after LN)
  ushort* vn      = (ushort*)(w + 100663296UL);     // 16.7MB
  ushort* vnT     = (ushort*)(w + 117440512UL);     // 16.7MB
  ushort* pv      = (ushort*)(w + 134217728UL);     // 16.7MB
  ushort* h       = (ushort*)(w + 150994944UL);     // 16.7MB
  ushort* wqT     = (ushort*)(w + 167772160UL);     // 1MB (512,1024)
  ushort* wkT     = (ushort*)(w + 168820736UL);
  ushort* wvT     = (ushort*)(w + 169869312UL);
  ushort* w1T     = (ushort*)(w + 170917888UL);     // 0.5MB (512,512)
  ushort* w2T     = (ushort*)(w + 171442176UL);     // 1MB (1024,512)
  float*  partial = (float*)(w + 172490752UL);      // 1MB: [8][16][2048]
  float*  invZ    = (float*)(w + 173539328UL);      // 64KB: [8][2048]

  dim3 blk(256);

  // weights -> bf16 transposed
  transpose_cvt_w3<<<dim3(16, 32, 3), blk, 0, stream>>>(Wq, Wk, Wv, wqT, wkT, wvT, 1024, 512);
  transpose_cvt_w<<<dim3(16, 16), blk, 0, stream>>>(W1, w1T, 512, 512);
  transpose_cvt_w<<<dim3(32, 16), blk, 0, stream>>>(W2, w2T, 512, 1024);

  // projections: f32 A with fused cvt
  gemm_tn<0, true, false, true><<<dim3(4, 128, 1), blk, 0, stream>>>(
      q, wqT, bq, nullptr, out_res, nullptr, nullptr, nullptr,
      16384, 512, 1024, 0, 0, 0, 0);
  gemm_tn<0, true, false, true><<<dim3(4, 128, 1), blk, 0, stream>>>(
      k, wkT, bk, nullptr, kp, nullptr, nullptr, nullptr,
      16384, 512, 1024, 0, 0, 0, 0);
  gemm_tn<0, true, false, true><<<dim3(4, 128, 1), blk, 0, stream>>>(
      v, wvT, bv, nullptr, vp, nullptr, nullptr, nullptr,
      16384, 512, 1024, 0, 0, 0, 0);

  // merged per-token LayerNorms (1/sqrt(DK) folded into qn)
  ln3_kernel<<<dim3(4096, 3), blk, 0, stream>>>(
      out_res, kp, vp, g_q, be_q, g_k, be_k, g_v, be_v, qn, kn, vn);

  // vn -> vnT for PV's B-operand
  transpose_bf16<<<dim3(16, 64, 8), blk, 0, stream>>>(vn, vnT, 2048, 512);

  // scores: exp(qn.kn^T) masked -> bf16 (unnormalized) + per-block row-sum partials
  gemm_tn<2, false, true, false><<<dim3(16, 16, 8), blk, 0, stream>>>(
      qn, kn, nullptr, mask, nullptr, attn_bf, partial, nullptr,
      2048, 2048, 512,
      (long)2048 * 512, (long)2048 * 512, (long)2048 * 2048, (long)2048 * 2048);

  // finalize: Z per row, write normalized f32 attn output + invZ
  softmax_finalize<<<16384, blk, 0, stream>>>(attn_bf, partial, out_attn, invZ);

  // PV with invZ row-scale epilogue
  gemm_tn<3, false, true, false><<<dim3(4, 16, 8), blk, 0, stream>>>(
      attn_bf, vnT, nullptr, nullptr, nullptr, pv, nullptr, invZ,
      2048, 512, 2048,
      (long)2048 * 2048, (long)512 * 2048, (long)2048 * 512, 0);

  // MLP
  gemm_tn<1, true, true, false><<<dim3(4, 128, 1), blk, 0, stream>>>(
      pv, w1T, b1, nullptr, nullptr, h, nullptr, nullptr,
      16384, 512, 512, 0, 0, 0, 0);
  gemm_tn<0, true, false, false><<<dim3(8, 128, 1), blk, 0, stream>>>(
      h, w2T, b2, nullptr, out_mlp, nullptr, nullptr, nullptr,
      16384, 1024, 512, 0, 0, 0, 0);
}

// Round 4
// 421.775 us; speedup vs baseline: 1.1389x; 1.0061x over previous
//
#include <hip/hip_runtime.h>
#include <hip/hip_bf16.h>

typedef __attribute__((ext_vector_type(8))) short short8;
typedef __attribute__((ext_vector_type(4))) short short4v;
typedef __attribute__((ext_vector_type(4))) float f32x4;

#define INV_TEMP 0.044194173824159216f

__device__ __forceinline__ ushort f2bf(float f) {
  unsigned u = __float_as_uint(f);
  unsigned r = (u + 0x7FFFu + ((u >> 16) & 1u)) >> 16;   // RNE
  return (ushort)r;
}
__device__ __forceinline__ float bf2f(ushort u) {
  union { unsigned i; float f; } x; x.i = ((unsigned)u) << 16; return x.f;
}

// async global->LDS, 16B per lane. LDS dest = wave-uniform base + lane*16;
// global source is per-lane (so source carries the inverse swizzle).
__device__ __forceinline__ void gload_lds16(const void* g, void* l) {
  __builtin_amdgcn_global_load_lds(
      (const __attribute__((address_space(1))) unsigned int*)(unsigned long long)(uintptr_t)g,
      (__attribute__((address_space(3))) unsigned int*)(unsigned)(uintptr_t)l,
      16, 0, 0);
}

// ---------------- all weight transposes in one launch ----------------
// z: 0=Wq(1024,512) 1=Wk 2=Wv 3=W1(512,512) 4=W2(512,1024); W(K,N)->WT(N,K) bf16
__global__ __launch_bounds__(256)
void transpose_cvt_all(const float* __restrict__ Wq, const float* __restrict__ Wk,
                       const float* __restrict__ Wv, const float* __restrict__ W1,
                       const float* __restrict__ W2,
                       ushort* __restrict__ Tq, ushort* __restrict__ Tk,
                       ushort* __restrict__ Tv, ushort* __restrict__ T1,
                       ushort* __restrict__ T2) {
  const int z = blockIdx.z;
  const int K = (z < 3) ? 1024 : 512;
  const int N = (z == 4) ? 1024 : 512;
  if (blockIdx.x * 32 >= N || blockIdx.y * 32 >= K) return;
  const float* W = z == 0 ? Wq : (z == 1 ? Wk : (z == 2 ? Wv : (z == 3 ? W1 : W2)));
  ushort* WT = z == 0 ? Tq : (z == 1 ? Tk : (z == 2 ? Tv : (z == 3 ? T1 : T2)));
  __shared__ float tile[32][33];
  const int n0 = blockIdx.x * 32, k0 = blockIdx.y * 32;
  const int tx = threadIdx.x & 31, ty = threadIdx.x >> 5;
  #pragma unroll
  for (int i = ty; i < 32; i += 8)
    tile[i][tx] = W[(long)(k0 + i) * N + n0 + tx];
  __syncthreads();
  #pragma unroll
  for (int i = ty; i < 32; i += 8)
    WT[(long)(n0 + i) * K + k0 + tx] = f2bf(tile[tx][i]);
}

// ---------------- bf16 transpose per batch: in (S,D) -> out (D,S) ----------------
__global__ __launch_bounds__(256)
void transpose_bf16(const ushort* __restrict__ in, ushort* __restrict__ out, int S, int D) {
  __shared__ ushort tile[32][33];
  const ushort* inb = in + (long)blockIdx.z * S * D;
  ushort* outb = out + (long)blockIdx.z * S * D;
  const int d0 = blockIdx.x * 32, s0 = blockIdx.y * 32;
  const int tx = threadIdx.x & 31, ty = threadIdx.x >> 5;
  #pragma unroll
  for (int i = ty; i < 32; i += 8)
    tile[i][tx] = inb[(long)(s0 + i) * D + d0 + tx];
  __syncthreads();
  #pragma unroll
  for (int i = ty; i < 32; i += 8)
    outb[(long)(d0 + i) * S + s0 + tx] = tile[tx][i];
}

// ---------------- merged LayerNorm over D=512: q from f32, k/v from bf16 ----------------
__global__ __launch_bounds__(256)
void ln3_kernel(const float* __restrict__ Xq, const ushort* __restrict__ Xk,
                const ushort* __restrict__ Xv,
                const float* __restrict__ gq, const float* __restrict__ beq,
                const float* __restrict__ gk, const float* __restrict__ bek,
                const float* __restrict__ gv, const float* __restrict__ bev,
                ushort* __restrict__ Oq, ushort* __restrict__ Ok, ushort* __restrict__ Ov) {
  const int which = blockIdx.y;
  const float* g = which == 0 ? gq : (which == 1 ? gk : gv);
  const float* be = which == 0 ? beq : (which == 1 ? bek : bev);
  ushort* out = which == 0 ? Oq : (which == 1 ? Ok : Ov);
  const float scale = which == 0 ? INV_TEMP : 1.0f;

  const int row = blockIdx.x * 4 + (threadIdx.x >> 6);
  const int lane = threadIdx.x & 63;
  f32x4 v0, v1;
  if (which == 0) {
    const float* x = Xq + (long)row * 512 + lane * 8;
    v0 = *(const f32x4*)x;
    v1 = *(const f32x4*)(x + 4);
  } else {
    const ushort* x = (which == 1 ? Xk : Xv) + (long)row * 512 + lane * 8;
    short8 vv = *(const short8*)x;
    #pragma unroll
    for (int j = 0; j < 4; j++) { v0[j] = bf2f((ushort)vv[j]); v1[j] = bf2f((ushort)vv[4 + j]); }
  }
  float s = v0[0]+v0[1]+v0[2]+v0[3]+v1[0]+v1[1]+v1[2]+v1[3];
  float ss = v0[0]*v0[0]+v0[1]*v0[1]+v0[2]*v0[2]+v0[3]*v0[3]
           + v1[0]*v1[0]+v1[1]*v1[1]+v1[2]*v1[2]+v1[3]*v1[3];
  #pragma unroll
  for (int off = 32; off; off >>= 1) { s += __shfl_xor(s, off); ss += __shfl_xor(ss, off); }
  const float mean = s * (1.0f/512.0f);
  const float var  = ss * (1.0f/512.0f) - mean*mean;
  const float rs = rsqrtf(var + 1e-6f);
  f32x4 g0 = *(const f32x4*)(g + lane*8);
  f32x4 g1 = *(const f32x4*)(g + lane*8 + 4);
  f32x4 b0 = *(const f32x4*)(be + lane*8);
  f32x4 b1 = *(const f32x4*)(be + lane*8 + 4);
  union { short8 v; ushort u[8]; } o;
  #pragma unroll
  for (int j = 0; j < 4; j++) o.u[j]     = f2bf(((v0[j]-mean)*rs*g0[j] + b0[j]) * scale);
  #pragma unroll
  for (int j = 0; j < 4; j++) o.u[4 + j] = f2bf(((v1[j]-mean)*rs*g1[j] + b1[j]) * scale);
  *(short8*)(out + (long)row * 512 + lane * 8) = o.v;
}

// ---------------- invZ from per-block partial row sums ----------------
__global__ __launch_bounds__(256)
void invz_reduce(const float* __restrict__ partial, float* __restrict__ invZ) {
  const int r = blockIdx.x * 256 + threadIdx.x;     // 0..16383 = zb*2048 + s
  const int zb = r >> 11, s = r & 2047;
  float z = 0.f;
  #pragma unroll
  for (int j = 0; j < 16; j++) z += partial[((zb * 16 + j) << 11) + s];
  invZ[r] = 1.0f / z;
}

// ---------------- TN GEMM: C[M,N] = A[M,K] * BT[N,K]^T (+bias, epilogue) ----------------
// EPI: 0 none, 1 relu, 2 exp+mask+row-sum partials (scores),
//      3 invZ row-scale (PV) + fused normalized-f32-attn write from bx==0 blocks
// A_F32: A is f32, reg-staged with fused cvt (swizzled ds_write); else global_load_lds.
template<int EPI, bool HAS_BIAS, bool OUT_BF16, bool A_F32>
__global__ __launch_bounds__(256)
void gemm_tn(const void* __restrict__ Av, const ushort* __restrict__ Bt,
             const float* __restrict__ bias, const int* __restrict__ mask,
             float* __restrict__ Cf, ushort* __restrict__ Cb,
             float* __restrict__ partial, const float* __restrict__ invZ,
             int M, int N, int K,
             long sA, long sB, long sC, long sMask) {
  __shared__ ushort As[128 * 64];
  __shared__ ushort Bs[128 * 64];
  __shared__ float zloc[128];
  const int tid = threadIdx.x;
  const int lane = tid & 63;
  const int wave = tid >> 6;
  const int wr = wave >> 1, wc = wave & 1;

  // ---- XCD-aware bijective chunk swizzle on linearized block index (T1) ----
  const int gx = gridDim.x, gy = gridDim.y;
  int lin = blockIdx.x + gx * (blockIdx.y + gy * blockIdx.z);
  const int nwg = gx * gy * (int)gridDim.z;
  int swz = lin;
  if ((nwg & 7) == 0) {
    const int q8 = nwg >> 3;
    swz = (lin & 7) * q8 + (lin >> 3);
  }
  const int bx = swz % gx;
  const int tmp = swz / gx;
  const int by = tmp % gy;
  const int bz = tmp / gy;

  const long zb = bz;
  const ushort* Ab = (const ushort*)Av + zb * sA + (long)by * 128 * K;
  const float*  Af = (const float*)Av + zb * sA + (long)by * 128 * K;
  const ushort* Bb = Bt + zb * sB + (long)bx * 128 * K;
  const int rowbase0 = by * 128;

  if constexpr (EPI == 3) {
    if (tid < 128) zloc[tid] = invZ[zb * 2048 + rowbase0 + tid];
  }

  f32x4 acc[4][4];
  #pragma unroll
  for (int m = 0; m < 4; m++)
    #pragma unroll
    for (int n = 0; n < 4; n++)
      acc[m][n] = f32x4{0.f, 0.f, 0.f, 0.f};

  for (int kt = 0; kt < K; kt += 64) {
    #pragma unroll
    for (int i = 0; i < 4; i++) {
      const int c = i * 256 + tid;            // 0..1023 granules of 16B
      const int row = c >> 3;
      const int g = c & 7;
      const int gsrc = g ^ (row & 7);
      gload_lds16(Bb + (long)row * K + kt + gsrc * 8, (char*)Bs + c * 16);
      if constexpr (A_F32) {
        const f32x4 u0 = *(const f32x4*)(Af + (long)row * K + kt + g * 8);
        const f32x4 u1 = *(const f32x4*)(Af + (long)row * K + kt + g * 8 + 4);
        union { short8 s; ushort u[8]; } o;
        #pragma unroll
        for (int j = 0; j < 4; j++) { o.u[j] = f2bf(u0[j]); o.u[4 + j] = f2bf(u1[j]); }
        *(short8*)((char*)As + ((row << 7) | ((g << 4) ^ ((row & 7) << 4)))) = o.s;
      } else {
        gload_lds16(Ab + (long)row * K + kt + gsrc * 8, (char*)As + c * 16);
      }
    }
    __syncthreads();   // also covers zloc init before first readback

    // fused attn f32 write: bx==0 blocks emit normalized attn from staged tile
    if constexpr (EPI == 3) {
      if (bx == 0) {
        #pragma unroll
        for (int i = 0; i < 4; i++) {
          const int c = i * 256 + tid;
          const int row = c >> 3;
          const int j = c & 7;
          short8 p8 = *(const short8*)((const char*)As + ((row << 7) | ((j ^ (row & 7)) << 4)));
          const float iz = zloc[row];
          f32x4 o0, o1;
          #pragma unroll
          for (int jj = 0; jj < 4; jj++) {
            o0[jj] = bf2f((ushort)p8[jj]) * iz;
            o1[jj] = bf2f((ushort)p8[4 + jj]) * iz;
          }
          float* dst = Cf + zb * 4194304L + (long)(rowbase0 + row) * 2048 + kt + j * 8;
          *(f32x4*)dst = o0;
          *(f32x4*)(dst + 4) = o1;
        }
      }
    }

    #pragma unroll
    for (int ks = 0; ks < 2; ks++) {
      short8 af[4], bfr[4];
      const int kb = ks * 64 + ((lane >> 4) << 4);
      #pragma unroll
      for (int m = 0; m < 4; m++) {
        const int row = wr * 64 + m * 16 + (lane & 15);
        af[m] = *(const short8*)((const char*)As + ((row << 7) | (kb ^ ((row & 7) << 4))));
      }
      #pragma unroll
      for (int n = 0; n < 4; n++) {
        const int col = wc * 64 + n * 16 + (lane & 15);
        bfr[n] = *(const short8*)((const char*)Bs + ((col << 7) | (kb ^ ((col & 7) << 4))));
      }
      #pragma unroll
      for (int m = 0; m < 4; m++)
        #pragma unroll
        for (int n = 0; n < 4; n++)
          acc[m][n] = __builtin_amdgcn_mfma_f32_16x16x32_bf16(af[m], bfr[n], acc[m][n], 0, 0, 0);
    }
    __syncthreads();
  }

  // epilogue: D[row][col], col = lane&15, row = (lane>>4)*4 + r  [m89/m91 layout]
  const int colbase = bx * 128 + wc * 64;
  const int rowbase = by * 128 + wr * 64;
  const int c_lane = lane & 15;
  const int r_lane = (lane >> 4) << 2;

  float rs_acc[4][4];
  if constexpr (EPI == 2) {
    #pragma unroll
    for (int m = 0; m < 4; m++)
      #pragma unroll
      for (int r4 = 0; r4 < 4; r4++) rs_acc[m][r4] = 0.f;
  }

  #pragma unroll
  for (int n = 0; n < 4; n++) {
    const int col = colbase + n * 16 + c_lane;
    const float bv = HAS_BIAS ? bias[col] : 0.0f;
    #pragma unroll
    for (int m = 0; m < 4; m++) {
      const int rbase = rowbase + m * 16 + r_lane;
      #pragma unroll
      for (int r4 = 0; r4 < 4; r4++) {
        const int row = rbase + r4;
        float vv = acc[m][n][r4] + bv;
        if constexpr (EPI == 1) vv = fmaxf(vv, 0.0f);
        if constexpr (EPI == 2) {
          const int mk = mask[zb * sMask + (long)row * N + col];
          vv = mk ? __expf(vv) : 0.0f;
          rs_acc[m][r4] += vv;
        }
        if constexpr (EPI == 3) vv *= zloc[wr * 64 + m * 16 + r_lane + r4];
        const long off = zb * sC + (long)row * N + col;
        if constexpr (OUT_BF16) Cb[off] = f2bf(vv);
        else                    Cf[off] = vv;
      }
    }
  }

  if constexpr (EPI == 2) {
    // deterministic per-block row sums: 16-lane group reduce -> LDS -> global
    float (*red)[128] = (float(*)[128])As;   // reuse As (all waves past final barrier)
    #pragma unroll
    for (int m = 0; m < 4; m++)
      #pragma unroll
      for (int r4 = 0; r4 < 4; r4++) {
        float vsum = rs_acc[m][r4];
        vsum += __shfl_xor(vsum, 1);
        vsum += __shfl_xor(vsum, 2);
        vsum += __shfl_xor(vsum, 4);
        vsum += __shfl_xor(vsum, 8);
        if (c_lane == 0) red[wc][wr * 64 + m * 16 + r_lane + r4] = vsum;
      }
    __syncthreads();
    if (tid < 128)
      partial[((long)zb * 16 + bx) * 2048 + by * 128 + tid] = red[0][tid] + red[1][tid];
  }
}

extern "C" void kernel_launch(void* const* d_in, const int* in_sizes, int n_in,
                              void* d_out, int out_size, void* d_ws, size_t ws_size,
                              hipStream_t stream) {
  const float* q    = (const float*)d_in[0];
  const float* k    = (const float*)d_in[1];
  const float* v    = (const float*)d_in[2];
  const int*   mask = (const int*)d_in[3];
  const float* Wq   = (const float*)d_in[4];
  const float* bq   = (const float*)d_in[5];
  const float* Wk   = (const float*)d_in[6];
  const float* bk   = (const float*)d_in[7];
  const float* Wv   = (const float*)d_in[8];
  const float* bv   = (const float*)d_in[9];
  const float* g_q  = (const float*)d_in[10];
  const float* be_q = (const float*)d_in[11];
  const float* g_k  = (const float*)d_in[12];
  const float* be_k = (const float*)d_in[13];
  const float* g_v  = (const float*)d_in[14];
  const float* be_v = (const float*)d_in[15];
  const float* W1   = (const float*)d_in[16];
  const float* b1   = (const float*)d_in[17];
  const float* W2   = (const float*)d_in[18];
  const float* b2   = (const float*)d_in[19];

  float* out_mlp  = (float*)d_out;                 // (8,2048,1024)
  float* out_res  = out_mlp + 16777216L;           // (8,2048,1,512)
  float* out_attn = out_res + 8388608L;            // (8,2048,2048)

  char* w = (char*)d_ws;
  ushort* qn      = (ushort*)(w);                   // 16.7MB
  ushort* kn      = (ushort*)(w + 16777216UL);      // 16.7MB
  ushort* kp_bf   = (ushort*)(w + 33554432UL);      // 16.7MB (dead after ln3)
  ushort* vp_bf   = (ushort*)(w + 50331648UL);      // 16.7MB (dead after ln3)
  ushort* attn_bf = (ushort*)(w + 33554432UL);      // 67MB, overlaps kp_bf/vp_bf
  ushort* vn      = (ushort*)(w + 100663296UL);     // 16.7MB
  ushort* vnT     = (ushort*)(w + 117440512UL);     // 16.7MB
  ushort* pv      = (ushort*)(w + 134217728UL);     // 16.7MB
  ushort* h       = (ushort*)(w + 150994944UL);     // 16.7MB
  ushort* wqT     = (ushort*)(w + 167772160UL);     // 1MB (512,1024)
  ushort* wkT     = (ushort*)(w + 168820736UL);
  ushort* wvT     = (ushort*)(w + 169869312UL);
  ushort* w1T     = (ushort*)(w + 170917888UL);     // 0.5MB (512,512)
  ushort* w2T     = (ushort*)(w + 171442176UL);     // 1MB (1024,512)
  float*  partial = (float*)(w + 172490752UL);      // 1MB: [8][16][2048]
  float*  invZ    = (float*)(w + 173539328UL);      // 64KB: [8][2048]

  dim3 blk(256);

  // all weight transposes, one launch
  transpose_cvt_all<<<dim3(32, 32, 5), blk, 0, stream>>>(
      Wq, Wk, Wv, W1, W2, wqT, wkT, wvT, w1T, w2T);

  // projections: f32 A with fused cvt; k/v write bf16 directly
  gemm_tn<0, true, false, true><<<dim3(4, 128, 1), blk, 0, stream>>>(
      q, wqT, bq, nullptr, out_res, nullptr, nullptr, nullptr,
      16384, 512, 1024, 0, 0, 0, 0);
  gemm_tn<0, true, true, true><<<dim3(4, 128, 1), blk, 0, stream>>>(
      k, wkT, bk, nullptr, nullptr, kp_bf, nullptr, nullptr,
      16384, 512, 1024, 0, 0, 0, 0);
  gemm_tn<0, true, true, true><<<dim3(4, 128, 1), blk, 0, stream>>>(
      v, wvT, bv, nullptr, nullptr, vp_bf, nullptr, nullptr,
      16384, 512, 1024, 0, 0, 0, 0);

  // merged per-token LayerNorms (1/sqrt(DK) folded into qn)
  ln3_kernel<<<dim3(4096, 3), blk, 0, stream>>>(
      out_res, kp_bf, vp_bf, g_q, be_q, g_k, be_k, g_v, be_v, qn, kn, vn);

  // vn -> vnT for PV's B-operand
  transpose_bf16<<<dim3(16, 64, 8), blk, 0, stream>>>(vn, vnT, 2048, 512);

  // scores: exp(qn.kn^T) masked -> bf16 (unnormalized) + per-block row-sum partials
  gemm_tn<2, false, true, false><<<dim3(16, 16, 8), blk, 0, stream>>>(
      qn, kn, nullptr, mask, nullptr, attn_bf, partial, nullptr,
      2048, 2048, 512,
      (long)2048 * 512, (long)2048 * 512, (long)2048 * 2048, (long)2048 * 2048);

  // invZ per row
  invz_reduce<<<64, blk, 0, stream>>>(partial, invZ);

  // PV with invZ row-scale epilogue + fused normalized f32 attn write (bx==0)
  gemm_tn<3, false, true, false><<<dim3(4, 16, 8), blk, 0, stream>>>(
      attn_bf, vnT, nullptr, nullptr, out_attn, pv, nullptr, invZ,
      2048, 512, 2048,
      (long)2048 * 2048, (long)512 * 2048, (long)2048 * 512, 0);

  // MLP
  gemm_tn<1, true, true, false><<<dim3(4, 128, 1), blk, 0, stream>>>(
      pv, w1T, b1, nullptr, nullptr, h, nullptr, nullptr,
      16384, 512, 512, 0, 0, 0, 0);
  gemm_tn<0, true, false, false><<<dim3(8, 128, 1), blk, 0, stream>>>(
      h, w2T, b2, nullptr, out_mlp, nullptr, nullptr, nullptr,
      16384, 1024, 512, 0, 0, 0, 0);
}

// Round 5
// 376.515 us; speedup vs baseline: 1.2758x; 1.1202x over previous
//
#include <hip/hip_runtime.h>
#include <hip/hip_bf16.h>

typedef __attribute__((ext_vector_type(8))) short short8;
typedef __attribute__((ext_vector_type(4))) short short4v;
typedef __attribute__((ext_vector_type(4))) float f32x4;

#define INV_TEMP 0.044194173824159216f

__device__ __forceinline__ ushort f2bf(float f) {
  unsigned u = __float_as_uint(f);
  unsigned r = (u + 0x7FFFu + ((u >> 16) & 1u)) >> 16;   // RNE
  return (ushort)r;
}
__device__ __forceinline__ float bf2f(ushort u) {
  union { unsigned i; float f; } x; x.i = ((unsigned)u) << 16; return x.f;
}

// async global->LDS, 16B per lane. LDS dest = wave-uniform base + lane*16;
// global source is per-lane (carries the inverse swizzle).
__device__ __forceinline__ void gload_lds16(const void* g, void* l) {
  __builtin_amdgcn_global_load_lds(
      (const __attribute__((address_space(1))) unsigned int*)(unsigned long long)(uintptr_t)g,
      (__attribute__((address_space(3))) unsigned int*)(unsigned)(uintptr_t)l,
      16, 0, 0);
}

// ---------------- all weight transposes in one launch ----------------
__global__ __launch_bounds__(256)
void transpose_cvt_all(const float* __restrict__ Wq, const float* __restrict__ Wk,
                       const float* __restrict__ Wv, const float* __restrict__ W1,
                       const float* __restrict__ W2,
                       ushort* __restrict__ Tq, ushort* __restrict__ Tk,
                       ushort* __restrict__ Tv, ushort* __restrict__ T1,
                       ushort* __restrict__ T2) {
  const int z = blockIdx.z;
  const int K = (z < 3) ? 1024 : 512;
  const int N = (z == 4) ? 1024 : 512;
  if (blockIdx.x * 32 >= N || blockIdx.y * 32 >= K) return;
  const float* W = z == 0 ? Wq : (z == 1 ? Wk : (z == 2 ? Wv : (z == 3 ? W1 : W2)));
  ushort* WT = z == 0 ? Tq : (z == 1 ? Tk : (z == 2 ? Tv : (z == 3 ? T1 : T2)));
  __shared__ float tile[32][33];
  const int n0 = blockIdx.x * 32, k0 = blockIdx.y * 32;
  const int tx = threadIdx.x & 31, ty = threadIdx.x >> 5;
  #pragma unroll
  for (int i = ty; i < 32; i += 8)
    tile[i][tx] = W[(long)(k0 + i) * N + n0 + tx];
  __syncthreads();
  #pragma unroll
  for (int i = ty; i < 32; i += 8)
    WT[(long)(n0 + i) * K + k0 + tx] = f2bf(tile[tx][i]);
}

// ---------------- bf16 transpose per batch: in (S,D) -> out (D,S) ----------------
__global__ __launch_bounds__(256)
void transpose_bf16(const ushort* __restrict__ in, ushort* __restrict__ out, int S, int D) {
  __shared__ ushort tile[32][33];
  const ushort* inb = in + (long)blockIdx.z * S * D;
  ushort* outb = out + (long)blockIdx.z * S * D;
  const int d0 = blockIdx.x * 32, s0 = blockIdx.y * 32;
  const int tx = threadIdx.x & 31, ty = threadIdx.x >> 5;
  #pragma unroll
  for (int i = ty; i < 32; i += 8)
    tile[i][tx] = inb[(long)(s0 + i) * D + d0 + tx];
  __syncthreads();
  #pragma unroll
  for (int i = ty; i < 32; i += 8)
    outb[(long)(d0 + i) * S + s0 + tx] = tile[tx][i];
}

// ---------------- merged LayerNorm over D=512: q from f32, k/v from bf16 ----------------
__global__ __launch_bounds__(256)
void ln3_kernel(const float* __restrict__ Xq, const ushort* __restrict__ Xk,
                const ushort* __restrict__ Xv,
                const float* __restrict__ gq, const float* __restrict__ beq,
                const float* __restrict__ gk, const float* __restrict__ bek,
                const float* __restrict__ gv, const float* __restrict__ bev,
                ushort* __restrict__ Oq, ushort* __restrict__ Ok, ushort* __restrict__ Ov) {
  const int which = blockIdx.y;
  const float* g = which == 0 ? gq : (which == 1 ? gk : gv);
  const float* be = which == 0 ? beq : (which == 1 ? bek : bev);
  ushort* out = which == 0 ? Oq : (which == 1 ? Ok : Ov);
  const float scale = which == 0 ? INV_TEMP : 1.0f;

  const int row = blockIdx.x * 4 + (threadIdx.x >> 6);
  const int lane = threadIdx.x & 63;
  f32x4 v0, v1;
  if (which == 0) {
    const float* x = Xq + (long)row * 512 + lane * 8;
    v0 = *(const f32x4*)x;
    v1 = *(const f32x4*)(x + 4);
  } else {
    const ushort* x = (which == 1 ? Xk : Xv) + (long)row * 512 + lane * 8;
    short8 vv = *(const short8*)x;
    #pragma unroll
    for (int j = 0; j < 4; j++) { v0[j] = bf2f((ushort)vv[j]); v1[j] = bf2f((ushort)vv[4 + j]); }
  }
  float s = v0[0]+v0[1]+v0[2]+v0[3]+v1[0]+v1[1]+v1[2]+v1[3];
  float ss = v0[0]*v0[0]+v0[1]*v0[1]+v0[2]*v0[2]+v0[3]*v0[3]
           + v1[0]*v1[0]+v1[1]*v1[1]+v1[2]*v1[2]+v1[3]*v1[3];
  #pragma unroll
  for (int off = 32; off; off >>= 1) { s += __shfl_xor(s, off); ss += __shfl_xor(ss, off); }
  const float mean = s * (1.0f/512.0f);
  const float var  = ss * (1.0f/512.0f) - mean*mean;
  const float rs = rsqrtf(var + 1e-6f);
  f32x4 g0 = *(const f32x4*)(g + lane*8);
  f32x4 g1 = *(const f32x4*)(g + lane*8 + 4);
  f32x4 b0 = *(const f32x4*)(be + lane*8);
  f32x4 b1 = *(const f32x4*)(be + lane*8 + 4);
  union { short8 v; ushort u[8]; } o;
  #pragma unroll
  for (int j = 0; j < 4; j++) o.u[j]     = f2bf(((v0[j]-mean)*rs*g0[j] + b0[j]) * scale);
  #pragma unroll
  for (int j = 0; j < 4; j++) o.u[4 + j] = f2bf(((v1[j]-mean)*rs*g1[j] + b1[j]) * scale);
  *(short8*)(out + (long)row * 512 + lane * 8) = o.v;
}

// ---------------- invZ from per-block partial row sums ----------------
__global__ __launch_bounds__(256)
void invz_reduce(const float* __restrict__ partial, float* __restrict__ invZ) {
  const int r = blockIdx.x * 256 + threadIdx.x;     // 0..16383 = zb*2048 + s
  const int zb = r >> 11, s = r & 2047;
  float z = 0.f;
  #pragma unroll
  for (int j = 0; j < 16; j++) z += partial[((zb * 16 + j) << 11) + s];
  invZ[r] = 1.0f / z;
}

// ---------------- pipelined TN GEMM: C[M,N] = A[M,K] * BT[N,K]^T ----------------
// 512 threads, 8 waves (2M x 4N), per-wave 64x32 output, BK=64, double-buffered
// LDS with 2-tile-ahead async staging and counted vmcnt (loads in flight across
// barriers; never vmcnt(0) in steady state).
// EPI: 0 none, 1 relu, 2 exp+mask+row-sum partials, 3 invZ row-scale + fused
//      normalized-f32-attn write (block bx writes column quarter bx).
template<int EPI, bool HAS_BIAS, bool OUT_BF16, bool A_F32>
__global__ __launch_bounds__(512)
void gemm_tn_pipe(const void* __restrict__ Av, const ushort* __restrict__ Bt,
                  const float* __restrict__ bias, const int* __restrict__ mask,
                  float* __restrict__ Cf, ushort* __restrict__ Cb,
                  float* __restrict__ partial, const float* __restrict__ invZ,
                  int M, int N, int K,
                  long sA, long sB, long sC, long sMask) {
  __shared__ ushort As[2][128 * 64];
  __shared__ ushort Bs[2][128 * 64];
  __shared__ float zloc[128];
  const int tid = threadIdx.x;
  const int lane = tid & 63;
  const int wave = tid >> 6;       // 0..7
  const int wr = wave >> 2;        // 0..1  (64-row slab)
  const int wc = wave & 3;         // 0..3  (32-col slab)

  // ---- XCD-aware bijective chunk swizzle (T1) ----
  const int gx = gridDim.x, gy = gridDim.y;
  int lin = blockIdx.x + gx * (blockIdx.y + gy * blockIdx.z);
  const int nwg = gx * gy * (int)gridDim.z;
  int swz = lin;
  if ((nwg & 7) == 0) {
    const int q8 = nwg >> 3;
    swz = (lin & 7) * q8 + (lin >> 3);
  }
  const int bx = swz % gx;
  const int tmp = swz / gx;
  const int by = tmp % gy;
  const int bz = tmp / gy;

  const long zb = bz;
  const ushort* Ab = (const ushort*)Av + zb * sA + (long)by * 128 * K;
  const float*  Af = (const float*)Av + zb * sA + (long)by * 128 * K;
  const ushort* Bb = Bt + zb * sB + (long)bx * 128 * K;
  const int rowbase0 = by * 128;
  const int nt = K >> 6;

  if constexpr (EPI == 3) {
    if (tid < 128) zloc[tid] = invZ[zb * 2048 + rowbase0 + tid];
  }

  // stage K-tile t into buffer buf. bf16: 4 async gloads (A0,B0,A1,B1).
  // A_F32: A f32 loads FIRST (so compiler's wait leaves B gloads in flight),
  // then 2 B gloads, then cvt + swizzled ds_write.
  auto stage = [&](int buf, int t) {
    const long kt = (long)t << 6;
    if constexpr (A_F32) {
      const int c0 = tid, c1 = 512 + tid;
      const float* p0 = Af + (long)(c0 >> 3) * K + kt + (c0 & 7) * 8;
      const float* p1 = Af + (long)(c1 >> 3) * K + kt + (c1 & 7) * 8;
      f32x4 a00 = *(const f32x4*)p0;
      f32x4 a01 = *(const f32x4*)(p0 + 4);
      f32x4 a10 = *(const f32x4*)p1;
      f32x4 a11 = *(const f32x4*)(p1 + 4);
      #pragma unroll
      for (int e = 0; e < 2; e++) {
        const int c = e * 512 + tid;
        const int row = c >> 3, g = c & 7, gsrc = g ^ (row & 7);
        gload_lds16(Bb + (long)row * K + kt + gsrc * 8, (char*)Bs[buf] + c * 16);
      }
      union { short8 s; ushort u[8]; } o0, o1;
      #pragma unroll
      for (int j = 0; j < 4; j++) {
        o0.u[j] = f2bf(a00[j]); o0.u[4 + j] = f2bf(a01[j]);
        o1.u[j] = f2bf(a10[j]); o1.u[4 + j] = f2bf(a11[j]);
      }
      const int r0 = c0 >> 3, g0 = c0 & 7, r1 = c1 >> 3, g1 = c1 & 7;
      *(short8*)((char*)As[buf] + ((r0 << 7) | ((g0 << 4) ^ ((r0 & 7) << 4)))) = o0.s;
      *(short8*)((char*)As[buf] + ((r1 << 7) | ((g1 << 4) ^ ((r1 & 7) << 4)))) = o1.s;
    } else {
      #pragma unroll
      for (int e = 0; e < 2; e++) {
        const int c = e * 512 + tid;
        const int row = c >> 3, g = c & 7, gsrc = g ^ (row & 7);
        gload_lds16(Ab + (long)row * K + kt + gsrc * 8, (char*)As[buf] + c * 16);
        gload_lds16(Bb + (long)row * K + kt + gsrc * 8, (char*)Bs[buf] + c * 16);
      }
    }
  };

  f32x4 acc[4][2];
  #pragma unroll
  for (int m = 0; m < 4; m++)
    #pragma unroll
    for (int n = 0; n < 2; n++)
      acc[m][n] = f32x4{0.f, 0.f, 0.f, 0.f};

  // prologue: two tiles in flight
  stage(0, 0);
  stage(1, 1);

  for (int t = 0; t < nt; ++t) {
    const int buf = t & 1;
    // drain exactly tile t's staging; leave tile t+1's in flight
    if (t == nt - 1) {
      asm volatile("s_waitcnt vmcnt(0)" ::: "memory");
    } else if constexpr (A_F32) {
      asm volatile("s_waitcnt vmcnt(2)" ::: "memory");
    } else {
      asm volatile("s_waitcnt vmcnt(4)" ::: "memory");
    }
    __builtin_amdgcn_s_barrier();          // all waves' tile-t data landed
    __builtin_amdgcn_sched_barrier(0);

    // fused normalized-attn f32 write (PV): block bx owns column quarter bx
    if constexpr (EPI == 3) {
      if ((t >> 3) == bx) {
        #pragma unroll
        for (int e = 0; e < 2; e++) {
          const int c = e * 512 + tid;
          const int row = c >> 3, g = c & 7;
          short8 p8 = *(const short8*)((const char*)As[buf] +
                       ((row << 7) | ((g ^ (row & 7)) << 4)));
          const float iz = zloc[row];
          f32x4 o0, o1;
          #pragma unroll
          for (int jj = 0; jj < 4; jj++) {
            o0[jj] = bf2f((ushort)p8[jj]) * iz;
            o1[jj] = bf2f((ushort)p8[4 + jj]) * iz;
          }
          float* dst = Cf + zb * 4194304L + (long)(rowbase0 + row) * 2048 + (t << 6) + g * 8;
          *(f32x4*)dst = o0;
          *(f32x4*)(dst + 4) = o1;
        }
      }
    }

    #pragma unroll
    for (int ks = 0; ks < 2; ks++) {
      short8 af[4], bfr[2];
      const int kb = ks * 64 + ((lane >> 4) << 4);
      #pragma unroll
      for (int m = 0; m < 4; m++) {
        const int row = wr * 64 + m * 16 + (lane & 15);
        af[m] = *(const short8*)((const char*)As[buf] +
                 ((row << 7) | (kb ^ ((row & 7) << 4))));
      }
      #pragma unroll
      for (int n = 0; n < 2; n++) {
        const int col = wc * 32 + n * 16 + (lane & 15);
        bfr[n] = *(const short8*)((const char*)Bs[buf] +
                  ((col << 7) | (kb ^ ((col & 7) << 4))));
      }
      #pragma unroll
      for (int m = 0; m < 4; m++)
        #pragma unroll
        for (int n = 0; n < 2; n++)
          acc[m][n] = __builtin_amdgcn_mfma_f32_16x16x32_bf16(af[m], bfr[n], acc[m][n], 0, 0, 0);
    }
    __builtin_amdgcn_sched_barrier(0);
    __builtin_amdgcn_s_barrier();          // all waves done reading buf
    __builtin_amdgcn_sched_barrier(0);
    if (t + 2 < nt) stage(buf, t + 2);     // overwrite just-read buffer
  }

  // epilogue: D[row][col], col = lane&15, row = (lane>>4)*4 + r  [m89/m91 layout]
  const int colbase = bx * 128 + wc * 32;
  const int rowbase = by * 128 + wr * 64;
  const int c_lane = lane & 15;
  const int r_lane = (lane >> 4) << 2;

  float rs_acc[4][4];
  if constexpr (EPI == 2) {
    #pragma unroll
    for (int m = 0; m < 4; m++)
      #pragma unroll
      for (int r4 = 0; r4 < 4; r4++) rs_acc[m][r4] = 0.f;
  }

  #pragma unroll
  for (int n = 0; n < 2; n++) {
    const int col = colbase + n * 16 + c_lane;
    const float bv = HAS_BIAS ? bias[col] : 0.0f;
    #pragma unroll
    for (int m = 0; m < 4; m++) {
      const int rbase = rowbase + m * 16 + r_lane;
      #pragma unroll
      for (int r4 = 0; r4 < 4; r4++) {
        const int row = rbase + r4;
        float vv = acc[m][n][r4] + bv;
        if constexpr (EPI == 1) vv = fmaxf(vv, 0.0f);
        if constexpr (EPI == 2) {
          const int mk = mask[zb * sMask + (long)row * N + col];
          vv = mk ? __expf(vv) : 0.0f;
          rs_acc[m][r4] += vv;
        }
        if constexpr (EPI == 3) vv *= zloc[wr * 64 + m * 16 + r_lane + r4];
        const long off = zb * sC + (long)row * N + col;
        if constexpr (OUT_BF16) Cb[off] = f2bf(vv);
        else                    Cf[off] = vv;
      }
    }
  }

  if constexpr (EPI == 2) {
    // deterministic per-block row sums: 16-lane reduce -> LDS -> sum 4 wc waves
    __syncthreads();                        // As free for reuse as scratch
    float (*red)[128] = (float(*)[128])As;
    #pragma unroll
    for (int m = 0; m < 4; m++)
      #pragma unroll
      for (int r4 = 0; r4 < 4; r4++) {
        float vsum = rs_acc[m][r4];
        vsum += __shfl_xor(vsum, 1);
        vsum += __shfl_xor(vsum, 2);
        vsum += __shfl_xor(vsum, 4);
        vsum += __shfl_xor(vsum, 8);
        if (c_lane == 0) red[wc][wr * 64 + m * 16 + r_lane + r4] = vsum;
      }
    __syncthreads();
    if (tid < 128)
      partial[((long)zb * 16 + bx) * 2048 + by * 128 + tid] =
          red[0][tid] + red[1][tid] + red[2][tid] + red[3][tid];
  }
}

extern "C" void kernel_launch(void* const* d_in, const int* in_sizes, int n_in,
                              void* d_out, int out_size, void* d_ws, size_t ws_size,
                              hipStream_t stream) {
  const float* q    = (const float*)d_in[0];
  const float* k    = (const float*)d_in[1];
  const float* v    = (const float*)d_in[2];
  const int*   mask = (const int*)d_in[3];
  const float* Wq   = (const float*)d_in[4];
  const float* bq   = (const float*)d_in[5];
  const float* Wk   = (const float*)d_in[6];
  const float* bk   = (const float*)d_in[7];
  const float* Wv   = (const float*)d_in[8];
  const float* bv   = (const float*)d_in[9];
  const float* g_q  = (const float*)d_in[10];
  const float* be_q = (const float*)d_in[11];
  const float* g_k  = (const float*)d_in[12];
  const float* be_k = (const float*)d_in[13];
  const float* g_v  = (const float*)d_in[14];
  const float* be_v = (const float*)d_in[15];
  const float* W1   = (const float*)d_in[16];
  const float* b1   = (const float*)d_in[17];
  const float* W2   = (const float*)d_in[18];
  const float* b2   = (const float*)d_in[19];

  float* out_mlp  = (float*)d_out;                 // (8,2048,1024)
  float* out_res  = out_mlp + 16777216L;           // (8,2048,1,512)
  float* out_attn = out_res + 8388608L;            // (8,2048,2048)

  char* w = (char*)d_ws;
  ushort* qn      = (ushort*)(w);                   // 16.7MB
  ushort* kn      = (ushort*)(w + 16777216UL);      // 16.7MB
  ushort* kp_bf   = (ushort*)(w + 33554432UL);      // 16.7MB (dead after ln3)
  ushort* vp_bf   = (ushort*)(w + 50331648UL);      // 16.7MB (dead after ln3)
  ushort* attn_bf = (ushort*)(w + 33554432UL);      // 67MB, overlaps kp_bf/vp_bf
  ushort* vn      = (ushort*)(w + 100663296UL);     // 16.7MB
  ushort* vnT     = (ushort*)(w + 117440512UL);     // 16.7MB
  ushort* pv      = (ushort*)(w + 134217728UL);     // 16.7MB
  ushort* h       = (ushort*)(w + 150994944UL);     // 16.7MB
  ushort* wqT     = (ushort*)(w + 167772160UL);     // 1MB (512,1024)
  ushort* wkT     = (ushort*)(w + 168820736UL);
  ushort* wvT     = (ushort*)(w + 169869312UL);
  ushort* w1T     = (ushort*)(w + 170917888UL);     // 0.5MB (512,512)
  ushort* w2T     = (ushort*)(w + 171442176UL);     // 1MB (1024,512)
  float*  partial = (float*)(w + 172490752UL);      // 1MB: [8][16][2048]
  float*  invZ    = (float*)(w + 173539328UL);      // 64KB: [8][2048]

  dim3 blk(256);
  dim3 blk512(512);

  // all weight transposes, one launch
  transpose_cvt_all<<<dim3(32, 32, 5), blk, 0, stream>>>(
      Wq, Wk, Wv, W1, W2, wqT, wkT, wvT, w1T, w2T);

  // projections: f32 A with fused cvt; k/v write bf16 directly
  gemm_tn_pipe<0, true, false, true><<<dim3(4, 128, 1), blk512, 0, stream>>>(
      q, wqT, bq, nullptr, out_res, nullptr, nullptr, nullptr,
      16384, 512, 1024, 0, 0, 0, 0);
  gemm_tn_pipe<0, true, true, true><<<dim3(4, 128, 1), blk512, 0, stream>>>(
      k, wkT, bk, nullptr, nullptr, kp_bf, nullptr, nullptr,
      16384, 512, 1024, 0, 0, 0, 0);
  gemm_tn_pipe<0, true, true, true><<<dim3(4, 128, 1), blk512, 0, stream>>>(
      v, wvT, bv, nullptr, nullptr, vp_bf, nullptr, nullptr,
      16384, 512, 1024, 0, 0, 0, 0);

  // merged per-token LayerNorms (1/sqrt(DK) folded into qn)
  ln3_kernel<<<dim3(4096, 3), blk, 0, stream>>>(
      out_res, kp_bf, vp_bf, g_q, be_q, g_k, be_k, g_v, be_v, qn, kn, vn);

  // vn -> vnT for PV's B-operand
  transpose_bf16<<<dim3(16, 64, 8), blk, 0, stream>>>(vn, vnT, 2048, 512);

  // scores: exp(qn.kn^T) masked -> bf16 (unnormalized) + per-block row-sum partials
  gemm_tn_pipe<2, false, true, false><<<dim3(16, 16, 8), blk512, 0, stream>>>(
      qn, kn, nullptr, mask, nullptr, attn_bf, partial, nullptr,
      2048, 2048, 512,
      (long)2048 * 512, (long)2048 * 512, (long)2048 * 2048, (long)2048 * 2048);

  // invZ per row
  invz_reduce<<<64, blk, 0, stream>>>(partial, invZ);

  // PV with invZ row-scale epilogue + fused normalized f32 attn write (balanced)
  gemm_tn_pipe<3, false, true, false><<<dim3(4, 16, 8), blk512, 0, stream>>>(
      attn_bf, vnT, nullptr, nullptr, out_attn, pv, nullptr, invZ,
      2048, 512, 2048,
      (long)2048 * 2048, (long)512 * 2048, (long)2048 * 512, 0);

  // MLP
  gemm_tn_pipe<1, true, true, false><<<dim3(4, 128, 1), blk512, 0, stream>>>(
      pv, w1T, b1, nullptr, nullptr, h, nullptr, nullptr,
      16384, 512, 512, 0, 0, 0, 0);
  gemm_tn_pipe<0, true, false, false><<<dim3(8, 128, 1), blk512, 0, stream>>>(
      h, w2T, b2, nullptr, out_mlp, nullptr, nullptr, nullptr,
      16384, 1024, 512, 0, 0, 0, 0);
}

// Round 6
// 369.995 us; speedup vs baseline: 1.2983x; 1.0176x over previous
//
#include <hip/hip_runtime.h>
#include <hip/hip_bf16.h>

typedef __attribute__((ext_vector_type(8))) short short8;
typedef __attribute__((ext_vector_type(4))) short short4v;
typedef __attribute__((ext_vector_type(4))) float f32x4;

#define INV_TEMP 0.044194173824159216f

__device__ __forceinline__ ushort f2bf(float f) {
  unsigned u = __float_as_uint(f);
  unsigned r = (u + 0x7FFFu + ((u >> 16) & 1u)) >> 16;   // RNE
  return (ushort)r;
}
__device__ __forceinline__ float bf2f(ushort u) {
  union { unsigned i; float f; } x; x.i = ((unsigned)u) << 16; return x.f;
}

// async global->LDS, 16B per lane. LDS dest = wave-uniform base + lane*16;
// global source is per-lane (carries the inverse swizzle).
__device__ __forceinline__ void gload_lds16(const void* g, void* l) {
  __builtin_amdgcn_global_load_lds(
      (const __attribute__((address_space(1))) unsigned int*)(unsigned long long)(uintptr_t)g,
      (__attribute__((address_space(3))) unsigned int*)(unsigned)(uintptr_t)l,
      16, 0, 0);
}

// ---------------- all weight transposes in one launch ----------------
__global__ __launch_bounds__(256)
void transpose_cvt_all(const float* __restrict__ Wq, const float* __restrict__ Wk,
                       const float* __restrict__ Wv, const float* __restrict__ W1,
                       const float* __restrict__ W2,
                       ushort* __restrict__ Tq, ushort* __restrict__ Tk,
                       ushort* __restrict__ Tv, ushort* __restrict__ T1,
                       ushort* __restrict__ T2) {
  const int z = blockIdx.z;
  const int K = (z < 3) ? 1024 : 512;
  const int N = (z == 4) ? 1024 : 512;
  if (blockIdx.x * 32 >= N || blockIdx.y * 32 >= K) return;
  const float* W = z == 0 ? Wq : (z == 1 ? Wk : (z == 2 ? Wv : (z == 3 ? W1 : W2)));
  ushort* WT = z == 0 ? Tq : (z == 1 ? Tk : (z == 2 ? Tv : (z == 3 ? T1 : T2)));
  __shared__ float tile[32][33];
  const int n0 = blockIdx.x * 32, k0 = blockIdx.y * 32;
  const int tx = threadIdx.x & 31, ty = threadIdx.x >> 5;
  #pragma unroll
  for (int i = ty; i < 32; i += 8)
    tile[i][tx] = W[(long)(k0 + i) * N + n0 + tx];
  __syncthreads();
  #pragma unroll
  for (int i = ty; i < 32; i += 8)
    WT[(long)(n0 + i) * K + k0 + tx] = f2bf(tile[tx][i]);
}

// ---------------- bf16 transpose per batch: in (S,D) -> out (D,S) ----------------
__global__ __launch_bounds__(256)
void transpose_bf16(const ushort* __restrict__ in, ushort* __restrict__ out, int S, int D) {
  __shared__ ushort tile[32][33];
  const ushort* inb = in + (long)blockIdx.z * S * D;
  ushort* outb = out + (long)blockIdx.z * S * D;
  const int d0 = blockIdx.x * 32, s0 = blockIdx.y * 32;
  const int tx = threadIdx.x & 31, ty = threadIdx.x >> 5;
  #pragma unroll
  for (int i = ty; i < 32; i += 8)
    tile[i][tx] = inb[(long)(s0 + i) * D + d0 + tx];
  __syncthreads();
  #pragma unroll
  for (int i = ty; i < 32; i += 8)
    outb[(long)(d0 + i) * S + s0 + tx] = tile[tx][i];
}

// ---------------- merged LayerNorm over D=512: q from f32, k/v from bf16 ----------------
__global__ __launch_bounds__(256)
void ln3_kernel(const float* __restrict__ Xq, const ushort* __restrict__ Xk,
                const ushort* __restrict__ Xv,
                const float* __restrict__ gq, const float* __restrict__ beq,
                const float* __restrict__ gk, const float* __restrict__ bek,
                const float* __restrict__ gv, const float* __restrict__ bev,
                ushort* __restrict__ Oq, ushort* __restrict__ Ok, ushort* __restrict__ Ov) {
  const int which = blockIdx.y;
  const float* g = which == 0 ? gq : (which == 1 ? gk : gv);
  const float* be = which == 0 ? beq : (which == 1 ? bek : bev);
  ushort* out = which == 0 ? Oq : (which == 1 ? Ok : Ov);
  const float scale = which == 0 ? INV_TEMP : 1.0f;

  const int row = blockIdx.x * 4 + (threadIdx.x >> 6);
  const int lane = threadIdx.x & 63;
  f32x4 v0, v1;
  if (which == 0) {
    const float* x = Xq + (long)row * 512 + lane * 8;
    v0 = *(const f32x4*)x;
    v1 = *(const f32x4*)(x + 4);
  } else {
    const ushort* x = (which == 1 ? Xk : Xv) + (long)row * 512 + lane * 8;
    short8 vv = *(const short8*)x;
    #pragma unroll
    for (int j = 0; j < 4; j++) { v0[j] = bf2f((ushort)vv[j]); v1[j] = bf2f((ushort)vv[4 + j]); }
  }
  float s = v0[0]+v0[1]+v0[2]+v0[3]+v1[0]+v1[1]+v1[2]+v1[3];
  float ss = v0[0]*v0[0]+v0[1]*v0[1]+v0[2]*v0[2]+v0[3]*v0[3]
           + v1[0]*v1[0]+v1[1]*v1[1]+v1[2]*v1[2]+v1[3]*v1[3];
  #pragma unroll
  for (int off = 32; off; off >>= 1) { s += __shfl_xor(s, off); ss += __shfl_xor(ss, off); }
  const float mean = s * (1.0f/512.0f);
  const float var  = ss * (1.0f/512.0f) - mean*mean;
  const float rs = rsqrtf(var + 1e-6f);
  f32x4 g0 = *(const f32x4*)(g + lane*8);
  f32x4 g1 = *(const f32x4*)(g + lane*8 + 4);
  f32x4 b0 = *(const f32x4*)(be + lane*8);
  f32x4 b1 = *(const f32x4*)(be + lane*8 + 4);
  union { short8 v; ushort u[8]; } o;
  #pragma unroll
  for (int j = 0; j < 4; j++) o.u[j]     = f2bf(((v0[j]-mean)*rs*g0[j] + b0[j]) * scale);
  #pragma unroll
  for (int j = 0; j < 4; j++) o.u[4 + j] = f2bf(((v1[j]-mean)*rs*g1[j] + b1[j]) * scale);
  *(short8*)(out + (long)row * 512 + lane * 8) = o.v;
}

// ---------------- pipelined TN GEMM: C[M,N] = A[M,K] * BT[N,K]^T ----------------
// 256 threads, 4 waves (2M x 2N), per-wave 64x64 output (0.5 ds_read/MFMA),
// BK=64, double-buffered LDS, 2-tile-ahead async staging, counted vmcnt.
// EPI: 0 none, 1 relu, 2 exp+mask+row-sum partials,
//      3 invZ-from-partials row-scale + fused normalized-f32-attn write,
//      4 merged QKV projections (grid z selects A/B/bias/output; A is f32).
template<int EPI, bool HAS_BIAS, bool OUT_BF16, bool A_F32>
__global__ __launch_bounds__(256)
void gemm_tn_pipe(const void* __restrict__ Av, const ushort* __restrict__ Bt,
                  const float* __restrict__ bias, const int* __restrict__ mask,
                  float* __restrict__ Cf, ushort* __restrict__ Cb,
                  float* __restrict__ partial,
                  const float* __restrict__ A2, const float* __restrict__ A3,
                  const ushort* __restrict__ Bt2, const ushort* __restrict__ Bt3,
                  const float* __restrict__ bias2, const float* __restrict__ bias3,
                  ushort* __restrict__ Cb2,
                  int M, int N, int K,
                  long sA, long sB, long sC, long sMask) {
  __shared__ ushort As[2][128 * 64];
  __shared__ ushort Bs[2][128 * 64];
  __shared__ float zloc[128];
  const int tid = threadIdx.x;
  const int lane = tid & 63;
  const int wave = tid >> 6;       // 0..3
  const int wr = wave >> 1;        // 0..1  (64-row slab)
  const int wc = wave & 1;         // 0..1  (64-col slab)

  // ---- XCD-aware bijective chunk swizzle (T1) ----
  const int gx = gridDim.x, gy = gridDim.y;
  int lin = blockIdx.x + gx * (blockIdx.y + gy * blockIdx.z);
  const int nwg = gx * gy * (int)gridDim.z;
  int swz = lin;
  if ((nwg & 7) == 0) {
    const int q8 = nwg >> 3;
    swz = (lin & 7) * q8 + (lin >> 3);
  }
  const int bx = swz % gx;
  const int tmp = swz / gx;
  const int by = tmp % gy;
  const int bz = tmp / gy;

  const long zb = bz;
  const float* Afp;
  const ushort* Bb;
  const float* bias_p = bias;
  if constexpr (EPI == 4) {
    Afp = (bz == 0 ? (const float*)Av : (bz == 1 ? A2 : A3)) + (long)by * 128 * K;
    Bb = (bz == 0 ? Bt : (bz == 1 ? Bt2 : Bt3)) + (long)bx * 128 * K;
    bias_p = bz == 0 ? bias : (bz == 1 ? bias2 : bias3);
  } else {
    Afp = (const float*)Av + zb * sA + (long)by * 128 * K;
    Bb = Bt + zb * sB + (long)bx * 128 * K;
  }
  const ushort* Ab = (const ushort*)Av + zb * sA + (long)by * 128 * K;
  const int rowbase0 = by * 128;
  const int nt = K >> 6;

  if constexpr (EPI == 3) {
    // invZ computed in-kernel from the 16 per-column-block partial row sums
    if (tid < 128) {
      float z = 0.f;
      #pragma unroll
      for (int j = 0; j < 16; j++)
        z += partial[((long)(zb * 16 + j)) * 2048 + rowbase0 + tid];
      zloc[tid] = 1.0f / z;
    }
  }

  // stage K-tile t into buffer buf.
  // bf16: 8 async gloads (A,B x4). A_F32/EPI4: 8 f32x4 A loads -> 4 B gloads
  // -> cvt + swizzled ds_write x4 -> lgkmcnt(0) (cross-wave visibility).
  auto stage = [&](int buf, int t) {
    const long kt = (long)t << 6;
    if constexpr (A_F32) {
      f32x4 a[4][2];
      #pragma unroll
      for (int i = 0; i < 4; i++) {
        const int c = i * 256 + tid;
        const int row = c >> 3, g = c & 7;
        const float* p = Afp + (long)row * K + kt + g * 8;
        a[i][0] = *(const f32x4*)p;
        a[i][1] = *(const f32x4*)(p + 4);
      }
      #pragma unroll
      for (int i = 0; i < 4; i++) {
        const int c = i * 256 + tid;
        const int row = c >> 3, g = c & 7, gsrc = g ^ (row & 7);
        gload_lds16(Bb + (long)row * K + kt + gsrc * 8, (char*)Bs[buf] + c * 16);
      }
      #pragma unroll
      for (int i = 0; i < 4; i++) {
        const int c = i * 256 + tid;
        const int row = c >> 3, g = c & 7;
        union { short8 s; ushort u[8]; } o;
        #pragma unroll
        for (int j = 0; j < 4; j++) { o.u[j] = f2bf(a[i][0][j]); o.u[4 + j] = f2bf(a[i][1][j]); }
        *(short8*)((char*)As[buf] + ((row << 7) | ((g << 4) ^ ((row & 7) << 4)))) = o.s;
      }
      asm volatile("s_waitcnt lgkmcnt(0)" ::: "memory");
    } else {
      #pragma unroll
      for (int i = 0; i < 4; i++) {
        const int c = i * 256 + tid;
        const int row = c >> 3, g = c & 7, gsrc = g ^ (row & 7);
        gload_lds16(Ab + (long)row * K + kt + gsrc * 8, (char*)As[buf] + c * 16);
        gload_lds16(Bb + (long)row * K + kt + gsrc * 8, (char*)Bs[buf] + c * 16);
      }
    }
  };

  f32x4 acc[4][4];
  #pragma unroll
  for (int m = 0; m < 4; m++)
    #pragma unroll
    for (int n = 0; n < 4; n++)
      acc[m][n] = f32x4{0.f, 0.f, 0.f, 0.f};

  // prologue: two tiles in flight
  stage(0, 0);
  stage(1, 1);

  for (int t = 0; t < nt; ++t) {
    const int buf = t & 1;
    // drain tile t's staging; leave tile t+1's loads in flight (counted vmcnt)
    if (t == nt - 1) {
      asm volatile("s_waitcnt vmcnt(0)" ::: "memory");
    } else if constexpr (A_F32) {
      asm volatile("s_waitcnt vmcnt(4)" ::: "memory");
    } else {
      asm volatile("s_waitcnt vmcnt(8)" ::: "memory");
    }
    __builtin_amdgcn_s_barrier();          // tile-t data visible to all waves
    __builtin_amdgcn_sched_barrier(0);

    // fused normalized-attn f32 write (PV): block bx owns column quarter bx
    if constexpr (EPI == 3) {
      if ((t >> 3) == bx) {
        #pragma unroll
        for (int e = 0; e < 4; e++) {
          const int c = e * 256 + tid;
          const int row = c >> 3, g = c & 7;
          short8 p8 = *(const short8*)((const char*)As[buf] +
                       ((row << 7) | ((g ^ (row & 7)) << 4)));
          const float iz = zloc[row];
          f32x4 o0, o1;
          #pragma unroll
          for (int jj = 0; jj < 4; jj++) {
            o0[jj] = bf2f((ushort)p8[jj]) * iz;
            o1[jj] = bf2f((ushort)p8[4 + jj]) * iz;
          }
          float* dst = Cf + zb * 4194304L + (long)(rowbase0 + row) * 2048 + (t << 6) + g * 8;
          *(f32x4*)dst = o0;
          *(f32x4*)(dst + 4) = o1;
        }
      }
    }

    #pragma unroll
    for (int ks = 0; ks < 2; ks++) {
      short8 af[4], bfr[4];
      const int kb = ks * 64 + ((lane >> 4) << 4);
      #pragma unroll
      for (int m = 0; m < 4; m++) {
        const int row = wr * 64 + m * 16 + (lane & 15);
        af[m] = *(const short8*)((const char*)As[buf] +
                 ((row << 7) | (kb ^ ((row & 7) << 4))));
      }
      #pragma unroll
      for (int n = 0; n < 4; n++) {
        const int col = wc * 64 + n * 16 + (lane & 15);
        bfr[n] = *(const short8*)((const char*)Bs[buf] +
                  ((col << 7) | (kb ^ ((col & 7) << 4))));
      }
      #pragma unroll
      for (int m = 0; m < 4; m++)
        #pragma unroll
        for (int n = 0; n < 4; n++)
          acc[m][n] = __builtin_amdgcn_mfma_f32_16x16x32_bf16(af[m], bfr[n], acc[m][n], 0, 0, 0);
    }
    __builtin_amdgcn_sched_barrier(0);
    __builtin_amdgcn_s_barrier();          // all waves done reading buf
    __builtin_amdgcn_sched_barrier(0);
    if (t + 2 < nt) stage(buf, t + 2);     // overwrite just-read buffer
  }

  // epilogue: D[row][col], col = lane&15, row = (lane>>4)*4 + r  [m89/m91 layout]
  const int colbase = bx * 128 + wc * 64;
  const int rowbase = by * 128 + wr * 64;
  const int c_lane = lane & 15;
  const int r_lane = (lane >> 4) << 2;

  float rs_acc[4][4];
  if constexpr (EPI == 2) {
    #pragma unroll
    for (int m = 0; m < 4; m++)
      #pragma unroll
      for (int r4 = 0; r4 < 4; r4++) rs_acc[m][r4] = 0.f;
  }

  #pragma unroll
  for (int n = 0; n < 4; n++) {
    const int col = colbase + n * 16 + c_lane;
    const float bv = HAS_BIAS ? bias_p[col] : 0.0f;
    #pragma unroll
    for (int m = 0; m < 4; m++) {
      const int rbase = rowbase + m * 16 + r_lane;
      #pragma unroll
      for (int r4 = 0; r4 < 4; r4++) {
        const int row = rbase + r4;
        float vv = acc[m][n][r4] + bv;
        if constexpr (EPI == 1) vv = fmaxf(vv, 0.0f);
        if constexpr (EPI == 2) {
          const int mk = mask[zb * sMask + (long)row * N + col];
          vv = mk ? __expf(vv) : 0.0f;
          rs_acc[m][r4] += vv;
        }
        if constexpr (EPI == 3) vv *= zloc[wr * 64 + m * 16 + r_lane + r4];
        const long off = zb * sC + (long)row * N + col;
        if constexpr (EPI == 4) {
          if (bz == 0) Cf[off] = vv;
          else if (bz == 1) Cb[off] = f2bf(vv);
          else Cb2[off] = f2bf(vv);
        } else if constexpr (OUT_BF16) {
          Cb[off] = f2bf(vv);
        } else {
          Cf[off] = vv;
        }
      }
    }
  }

  if constexpr (EPI == 2) {
    // deterministic per-block row sums: 16-lane reduce -> LDS -> sum both wc waves
    __syncthreads();                        // As free for reuse as scratch
    float (*red)[128] = (float(*)[128])As;
    #pragma unroll
    for (int m = 0; m < 4; m++)
      #pragma unroll
      for (int r4 = 0; r4 < 4; r4++) {
        float vsum = rs_acc[m][r4];
        vsum += __shfl_xor(vsum, 1);
        vsum += __shfl_xor(vsum, 2);
        vsum += __shfl_xor(vsum, 4);
        vsum += __shfl_xor(vsum, 8);
        if (c_lane == 0) red[wc][wr * 64 + m * 16 + r_lane + r4] = vsum;
      }
    __syncthreads();
    if (tid < 128)
      partial[((long)zb * 16 + bx) * 2048 + by * 128 + tid] = red[0][tid] + red[1][tid];
  }
}

extern "C" void kernel_launch(void* const* d_in, const int* in_sizes, int n_in,
                              void* d_out, int out_size, void* d_ws, size_t ws_size,
                              hipStream_t stream) {
  const float* q    = (const float*)d_in[0];
  const float* k    = (const float*)d_in[1];
  const float* v    = (const float*)d_in[2];
  const int*   mask = (const int*)d_in[3];
  const float* Wq   = (const float*)d_in[4];
  const float* bq   = (const float*)d_in[5];
  const float* Wk   = (const float*)d_in[6];
  const float* bk   = (const float*)d_in[7];
  const float* Wv   = (const float*)d_in[8];
  const float* bv   = (const float*)d_in[9];
  const float* g_q  = (const float*)d_in[10];
  const float* be_q = (const float*)d_in[11];
  const float* g_k  = (const float*)d_in[12];
  const float* be_k = (const float*)d_in[13];
  const float* g_v  = (const float*)d_in[14];
  const float* be_v = (const float*)d_in[15];
  const float* W1   = (const float*)d_in[16];
  const float* b1   = (const float*)d_in[17];
  const float* W2   = (const float*)d_in[18];
  const float* b2   = (const float*)d_in[19];

  float* out_mlp  = (float*)d_out;                 // (8,2048,1024)
  float* out_res  = out_mlp + 16777216L;           // (8,2048,1,512)
  float* out_attn = out_res + 8388608L;            // (8,2048,2048)

  char* w = (char*)d_ws;
  ushort* qn      = (ushort*)(w);                   // 16.7MB
  ushort* kn      = (ushort*)(w + 16777216UL);      // 16.7MB
  ushort* kp_bf   = (ushort*)(w + 33554432UL);      // 16.7MB (dead after ln3)
  ushort* vp_bf   = (ushort*)(w + 50331648UL);      // 16.7MB (dead after ln3)
  ushort* attn_bf = (ushort*)(w + 33554432UL);      // 67MB, overlaps kp_bf/vp_bf
  ushort* vn      = (ushort*)(w + 100663296UL);     // 16.7MB
  ushort* vnT     = (ushort*)(w + 117440512UL);     // 16.7MB
  ushort* pv      = (ushort*)(w + 134217728UL);     // 16.7MB
  ushort* h       = (ushort*)(w + 150994944UL);     // 16.7MB
  ushort* wqT     = (ushort*)(w + 167772160UL);     // 1MB (512,1024)
  ushort* wkT     = (ushort*)(w + 168820736UL);
  ushort* wvT     = (ushort*)(w + 169869312UL);
  ushort* w1T     = (ushort*)(w + 170917888UL);     // 0.5MB (512,512)
  ushort* w2T     = (ushort*)(w + 171442176UL);     // 1MB (1024,512)
  float*  partial = (float*)(w + 172490752UL);      // 1MB: [8][16][2048]

  dim3 blk(256);

  // all weight transposes, one launch
  transpose_cvt_all<<<dim3(32, 32, 5), blk, 0, stream>>>(
      Wq, Wk, Wv, W1, W2, wqT, wkT, wvT, w1T, w2T);

  // merged QKV projections: one launch, grid z selects; q->f32, k/v->bf16
  gemm_tn_pipe<4, true, false, true><<<dim3(4, 128, 3), blk, 0, stream>>>(
      q, wqT, bq, nullptr, out_res, kp_bf, nullptr,
      k, v, wkT, wvT, bk, bv, vp_bf,
      16384, 512, 1024, 0, 0, 0, 0);

  // merged per-token LayerNorms (1/sqrt(DK) folded into qn)
  ln3_kernel<<<dim3(4096, 3), blk, 0, stream>>>(
      out_res, kp_bf, vp_bf, g_q, be_q, g_k, be_k, g_v, be_v, qn, kn, vn);

  // vn -> vnT for PV's B-operand
  transpose_bf16<<<dim3(16, 64, 8), blk, 0, stream>>>(vn, vnT, 2048, 512);

  // scores: exp(qn.kn^T) masked -> bf16 (unnormalized) + per-block row-sum partials
  gemm_tn_pipe<2, false, true, false><<<dim3(16, 16, 8), blk, 0, stream>>>(
      qn, kn, nullptr, mask, nullptr, attn_bf, partial,
      nullptr, nullptr, nullptr, nullptr, nullptr, nullptr, nullptr,
      2048, 2048, 512,
      (long)2048 * 512, (long)2048 * 512, (long)2048 * 2048, (long)2048 * 2048);

  // PV: invZ computed in-prologue from partials; row-scale epilogue +
  // fused normalized f32 attn write (block bx writes column quarter bx)
  gemm_tn_pipe<3, false, true, false><<<dim3(4, 16, 8), blk, 0, stream>>>(
      attn_bf, vnT, nullptr, nullptr, out_attn, pv, partial,
      nullptr, nullptr, nullptr, nullptr, nullptr, nullptr, nullptr,
      2048, 512, 2048,
      (long)2048 * 2048, (long)512 * 2048, (long)2048 * 512, 0);

  // MLP
  gemm_tn_pipe<1, true, true, false><<<dim3(4, 128, 1), blk, 0, stream>>>(
      pv, w1T, b1, nullptr, nullptr, h, nullptr,
      nullptr, nullptr, nullptr, nullptr, nullptr, nullptr, nullptr,
      16384, 512, 512, 0, 0, 0, 0);
  gemm_tn_pipe<0, true, false, false><<<dim3(8, 128, 1), blk, 0, stream>>>(
      h, w2T, b2, nullptr, out_mlp, nullptr, nullptr,
      nullptr, nullptr, nullptr, nullptr, nullptr, nullptr, nullptr,
      16384, 1024, 512, 0, 0, 0, 0);
}